// Round 10
// baseline (889.830 us; speedup 1.0000x reference)
//
#include <hip/hip_runtime.h>
#include <hip/hip_bf16.h>

typedef __bf16 bf16_t;
typedef __attribute__((ext_vector_type(8))) __bf16 bf16x8;
typedef __attribute__((ext_vector_type(4))) float f32x4;

#define B_SZ 512
#define T_SZ 128
#define C_SZ 768
#define H_SZ 12
#define D_SZ 64
#define M_SZ (B_SZ * T_SZ)      // 65536
#define NQKV (3 * C_SZ)          // 2304

// ---------------------------------------------------------------- convert (weights only now)
__global__ __launch_bounds__(256) void cvt_f32_bf16(
    const float* __restrict__ in, bf16_t* __restrict__ out, int n)
{
    int i = (blockIdx.x * blockDim.x + threadIdx.x) * 8;
    int stride = gridDim.x * blockDim.x * 8;
    for (; i < n; i += stride) {
        float4 a = *reinterpret_cast<const float4*>(in + i);
        float4 b = *reinterpret_cast<const float4*>(in + i + 4);
        bf16x8 o;
        o[0] = (bf16_t)a.x; o[1] = (bf16_t)a.y;
        o[2] = (bf16_t)a.z; o[3] = (bf16_t)a.w;
        o[4] = (bf16_t)b.x; o[5] = (bf16_t)b.y;
        o[6] = (bf16_t)b.z; o[7] = (bf16_t)b.w;
        *reinterpret_cast<bf16x8*>(out + i) = o;
    }
}

// ---------------------------------------------------------------- shared GEMM machinery
__device__ __forceinline__ void gload16(const bf16_t* g, const char* l)
{
    __builtin_amdgcn_global_load_lds(
        (const __attribute__((address_space(1))) void*)g,
        (__attribute__((address_space(3))) void*)l, 16, 0, 0);
}

#define BAR() do { asm volatile("" ::: "memory"); \
                   __builtin_amdgcn_s_barrier(); \
                   asm volatile("" ::: "memory"); } while (0)

#define VMC(n) asm volatile("s_waitcnt vmcnt(" #n ")" ::: "memory")

#define LGKMW() asm volatile("s_waitcnt lgkmcnt(0)" ::: "memory")

#define LGKM0() do { asm volatile("s_waitcnt lgkmcnt(0)" ::: "memory"); \
                     __builtin_amdgcn_sched_barrier(0); } while (0)

// register fragment loads (ds_read_b128; compiler schedules lgkm waits)
#define RD_A0(bb) do { _Pragma("unroll") for (int m_ = 0; m_ < 4; ++m_) { \
    af0[m_][0] = *(const bf16x8*)(rdAk0 + (bb)*32768 + m_*2048); \
    af0[m_][1] = *(const bf16x8*)(rdAk1 + (bb)*32768 + m_*2048); } } while (0)

#define RD_AY(bb) do { _Pragma("unroll") for (int m_ = 0; m_ < 4; ++m_) { \
    afY[m_][0] = *(const bf16x8*)(rdAk0 + (bb)*32768 + 8192 + m_*2048); \
    afY[m_][1] = *(const bf16x8*)(rdAk1 + (bb)*32768 + 8192 + m_*2048); } } while (0)

#define RD_B01(bb) do { _Pragma("unroll") for (int n_ = 0; n_ < 2; ++n_) { \
    b01[n_][0] = *(const bf16x8*)(rdBk0 + (bb)*32768 + n_*2048); \
    b01[n_][1] = *(const bf16x8*)(rdBk1 + (bb)*32768 + n_*2048); } } while (0)

#define RD_B23(bb) do { _Pragma("unroll") for (int n_ = 0; n_ < 2; ++n_) { \
    b23[n_][0] = *(const bf16x8*)(rdBk0 + (bb)*32768 + 4096 + n_*2048); \
    b23[n_][1] = *(const bf16x8*)(rdBk1 + (bb)*32768 + 4096 + n_*2048); } } while (0)

// stage half-tile hf of K-tile u into buffer bb (predicated on u < nt)
#define ST_A(bb, hf, u) do { if ((u) < nt) { \
    const bf16_t* s_ = pA + (size_t)((hf)*128) * K + (size_t)(u)*64; \
    char* d_ = ldsAw + (bb)*32768 + (hf)*16384; \
    gload16(s_, d_); gload16(s_ + (size_t)8*K, d_ + 1024); } } while (0)

#define ST_B(bb, hf, u) do { if ((u) < nt) { \
    const bf16_t* s_ = pB + (size_t)((hf)*128) * K + (size_t)(u)*64; \
    char* d_ = ldsBw + (bb)*32768 + (hf)*16384; \
    gload16(s_, d_); gload16(s_ + (size_t)8*K, d_ + 1024); } } while (0)

// quadrant: 16 MFMA on (A_, B_) into acc[mo..mo+3][no..no+1]
#define MFQ(A_, B_, mo, no) do { __builtin_amdgcn_s_setprio(1); \
    _Pragma("unroll") for (int m_ = 0; m_ < 4; ++m_) \
    _Pragma("unroll") for (int n_ = 0; n_ < 2; ++n_) { \
        acc[(mo)+m_][(no)+n_] = __builtin_amdgcn_mfma_f32_16x16x32_bf16( \
            A_[m_][0], B_[n_][0], acc[(mo)+m_][(no)+n_], 0, 0, 0); \
        acc[(mo)+m_][(no)+n_] = __builtin_amdgcn_mfma_f32_16x16x32_bf16( \
            A_[m_][1], B_[n_][1], acc[(mo)+m_][(no)+n_], 0, 0, 0); } \
    __builtin_amdgcn_s_setprio(0); } while (0)

// A f32 reg-staging: thread covers rows w*32 + r8 + 8j (j=0..3), 32 B f32 per row
#define ALOAD(u) do { if ((u) < nt) { \
    const float* s_ = pAf + (size_t)(u) * 64; \
    _Pragma("unroll") for (int j_ = 0; j_ < 4; ++j_) { \
        av[j_*2]   = *(const float4*)(s_ + (size_t)(8*j_) * K); \
        av[j_*2+1] = *(const float4*)(s_ + (size_t)(8*j_) * K + 4); } } } while (0)

#define AWRITE(u, bb) do { if ((u) < nt) { \
    _Pragma("unroll") for (int j_ = 0; j_ < 4; ++j_) { \
        bf16x8 o_; \
        o_[0] = (bf16_t)av[j_*2].x;   o_[1] = (bf16_t)av[j_*2].y; \
        o_[2] = (bf16_t)av[j_*2].z;   o_[3] = (bf16_t)av[j_*2].w; \
        o_[4] = (bf16_t)av[j_*2+1].x; o_[5] = (bf16_t)av[j_*2+1].y; \
        o_[6] = (bf16_t)av[j_*2+1].z; o_[7] = (bf16_t)av[j_*2+1].w; \
        *(bf16x8*)(ldsAwr + (bb)*32768 + j_*1024) = o_; } } } while (0)

// ---------------------------------------------------------------- GEMM1: A f32 fused-convert
// C[M,N](bf16) = cvt_bf16(A_f32[M,K]) * Bt[N,K]^T ; 256x256 tile, BK=64, 8 waves
__global__ __launch_bounds__(512, 2) void gemm1_f32a(
    const float* __restrict__ A, const bf16_t* __restrict__ Bt,
    bf16_t* __restrict__ Cout, int M, int N, int K, int nx)
{
    __shared__ char smem[131072];   // A: [buf][half][128][64]bf16 @0, B same @65536

    const int tid  = threadIdx.x;
    const int lane = tid & 63;
    const int w    = tid >> 6;
    const int wr   = w >> 2;
    const int wc   = w & 3;

    const int nwg = gridDim.x;
    int bid = blockIdx.x;
    if ((nwg & 7) == 0) bid = (bid & 7) * (nwg >> 3) + (bid >> 3);
    const int bx = bid % nx;
    const int by = bid / nx;
    const size_t bm = (size_t)by * 256;
    const size_t bn = (size_t)bx * 256;

    const int nt    = K >> 6;
    const int niter = nt >> 1;

    // ---- B staging (pre-swizzled global source, linear LDS dest)
    const int i3    = lane >> 3;
    const int colSw = ((lane & 7) ^ i3) * 8;
    const bf16_t* pB = Bt + (bn + (size_t)(w * 16 + i3)) * K + colSw;
    char* ldsBw = smem + 65536 + w * 2048;

    // ---- A staging (f32 global -> regs -> cvt -> swizzled ds_write)
    const int s8 = lane & 7;       // 16-B bf16 slot (= 32-B f32 chunk)
    const int r8 = lane >> 3;      // row&7 for this lane (constant across j)
    const float* pAf = A + (bm + (size_t)(w * 32 + r8)) * K + s8 * 8;
    char* ldsAwr = smem + (w >> 2) * 16384 + ((w & 3) * 32 + r8) * 128 + ((s8 ^ r8) * 16);

    // ---- read addresses (swizzle on read: byte ^= (row&7)<<4) — identical to R6
    const int lane_lo = lane & 15;
    const int sxr  = (lane & 7) << 4;
    const int cK0  = (((lane >> 4) * 16) ^ sxr);
    const int cK1  = cK0 ^ 64;
    const char* rdAk0 = smem + wr * 16384 + lane_lo * 128 + cK0;
    const char* rdAk1 = smem + wr * 16384 + lane_lo * 128 + cK1;
    const char* rdBk0 = smem + 65536 + (wc >> 1) * 16384 + ((wc & 1) * 64 + lane_lo) * 128 + cK0;
    const char* rdBk1 = smem + 65536 + (wc >> 1) * 16384 + ((wc & 1) * 64 + lane_lo) * 128 + cK1;

    f32x4  acc[8][4] = {};
    bf16x8 af0[4][2], afY[4][2], b01[2][2], b23[2][2];
    float4 av[8];

    // ---- prologue: tile0 A (regs->LDS) + B (gload); tile1 A-loads in flight
    ALOAD(0); AWRITE(0, 0);
    ST_B(0, 0, 0); ST_B(0, 1, 0);
    ALOAD(1);
    VMC(8);     // drain the 4 B-gloads (oldest); 8 A-loads stay in flight
    LGKMW();    // A ds_writes landed before barrier
    BAR();

    for (int it = 0; it < niter; ++it) {
        const int u = it * 2;
        const bool lastit = (it + 1 == niter);
        // ---- tile u (buf0); stage tile u+1 -> buf1 only (no mid-barrier needed)
        ST_B(1, 0, u + 1); ST_B(1, 1, u + 1);
        AWRITE(u + 1, 1);          // consumes av(u+1) [older than the STBs -> partial waits]
        ALOAD(u + 2);              // reuse av regs for next tile
        RD_A0(0); RD_B01(0); RD_B23(0); RD_AY(0);
        MFQ(af0, b01, 0, 0); MFQ(af0, b23, 0, 2);
        MFQ(afY, b01, 4, 0); MFQ(afY, b23, 4, 2);
        if (lastit) { VMC(0); } else { VMC(8); }   // drain B(u+1); A(u+2) stays
        LGKMW(); BAR();
        // ---- tile u+1 (buf1); stage tile u+2 -> buf0
        ST_B(0, 0, u + 2); ST_B(0, 1, u + 2);
        AWRITE(u + 2, 0);
        ALOAD(u + 3);
        RD_A0(1); RD_B01(1); RD_B23(1); RD_AY(1);
        MFQ(af0, b01, 0, 0); MFQ(af0, b23, 0, 2);
        MFQ(afY, b01, 4, 0); MFQ(afY, b23, 4, 2);
        if (lastit) { VMC(0); } else { VMC(8); }
        LGKMW(); BAR();
    }

    // ---- epilogue via LDS (R6): scalar ds_writes -> coalesced bf16x8 stores
    const int crow = (lane >> 4) * 4;
    const int ccol = lane & 15;
    char* ep = smem + w * 16384;
    #pragma unroll
    for (int n = 0; n < 4; ++n) {
        #pragma unroll
        for (int m = 0; m < 8; ++m)
            #pragma unroll
            for (int r = 0; r < 4; ++r)
                *(bf16_t*)(ep + (m * 16 + crow + r) * 128 + (n * 16 + ccol) * 2)
                    = (bf16_t)acc[m][n][r];
    }
    LGKM0();
    #pragma unroll
    for (int pass = 0; pass < 16; ++pass) {
        const int rloc = pass * 8 + (lane >> 3);
        const int ch   = lane & 7;
        bf16x8 v = *(const bf16x8*)(ep + rloc * 128 + ch * 16);
        *(bf16x8*)((char*)(Cout + (bm + wr * 128 + rloc) * (size_t)N + bn + wc * 64) + ch * 16) = v;
    }
}

// ---------------------------------------------------------------- GEMM (bf16 A) — R6 verbatim
template <bool BF16_OUT, bool BIAS>
__global__ __launch_bounds__(512, 2) void gemm256(
    const bf16_t* __restrict__ A, const bf16_t* __restrict__ Bt,
    void* __restrict__ Cout, const float* __restrict__ bias,
    int M, int N, int K, int nx)
{
    __shared__ char smem[131072];

    const int tid  = threadIdx.x;
    const int lane = tid & 63;
    const int w    = tid >> 6;
    const int wr   = w >> 2;
    const int wc   = w & 3;

    const int nwg = gridDim.x;
    int bid = blockIdx.x;
    if ((nwg & 7) == 0) bid = (bid & 7) * (nwg >> 3) + (bid >> 3);
    const int bx = bid % nx;
    const int by = bid / nx;
    const size_t bm = (size_t)by * 256;
    const size_t bn = (size_t)bx * 256;

    const int nt    = K >> 6;
    const int niter = nt >> 1;

    const int i3    = lane >> 3;
    const int colSw = ((lane & 7) ^ i3) * 8;
    const bf16_t* pA = A  + (bm + (size_t)(w * 16 + i3)) * K + colSw;
    const bf16_t* pB = Bt + (bn + (size_t)(w * 16 + i3)) * K + colSw;
    char* ldsAw = smem + w * 2048;
    char* ldsBw = smem + 65536 + w * 2048;

    const int lane_lo = lane & 15;
    const int sxr  = (lane & 7) << 4;
    const int cK0  = (((lane >> 4) * 16) ^ sxr);
    const int cK1  = cK0 ^ 64;
    const char* rdAk0 = smem + wr * 16384 + lane_lo * 128 + cK0;
    const char* rdAk1 = smem + wr * 16384 + lane_lo * 128 + cK1;
    const char* rdBk0 = smem + 65536 + (wc >> 1) * 16384 + ((wc & 1) * 64 + lane_lo) * 128 + cK0;
    const char* rdBk1 = smem + 65536 + (wc >> 1) * 16384 + ((wc & 1) * 64 + lane_lo) * 128 + cK1;

    f32x4  acc[8][4] = {};
    bf16x8 af0[4][2], afY[4][2], b01[2][2], b23[2][2];

    ST_B(0, 0, 0); ST_A(0, 0, 0); ST_A(0, 1, 0); ST_B(0, 1, 0);
    ST_B(1, 0, 1); ST_A(1, 0, 1);
    VMC(4);
    BAR();

    for (int it = 0; it < niter; ++it) {
        const int u = it * 2;
        const bool last = (it + 1 == niter);
        RD_A0(0); RD_B01(0); RD_B23(0); ST_A(1, 1, u + 1); MFQ(af0, b01, 0, 0); BAR();
        RD_AY(0);                        ST_B(1, 1, u + 1); MFQ(af0, b23, 0, 2); BAR();
                                         ST_B(0, 0, u + 2); MFQ(afY, b01, 4, 0); BAR();
                                         ST_A(0, 0, u + 2); MFQ(afY, b23, 4, 2);
        if (last) { VMC(0); } else { VMC(4); }
        BAR();
        RD_A0(1); RD_B01(1); RD_B23(1); ST_A(0, 1, u + 2); MFQ(af0, b01, 0, 0); BAR();
        RD_AY(1);                        ST_B(0, 1, u + 2); MFQ(af0, b23, 0, 2); BAR();
                                         ST_B(1, 0, u + 3); MFQ(afY, b01, 4, 0); BAR();
                                         ST_A(1, 0, u + 3); MFQ(afY, b23, 4, 2);
        if (last) { VMC(0); } else { VMC(4); }
        BAR();
    }

    const int crow = (lane >> 4) * 4;
    const int ccol = lane & 15;
    if constexpr (BF16_OUT) {
        char* ep = smem + w * 16384;
        #pragma unroll
        for (int n = 0; n < 4; ++n) {
            const size_t col = bn + wc * 64 + n * 16 + ccol;
            float bv = 0.f;
            if constexpr (BIAS) bv = bias[col];
            #pragma unroll
            for (int m = 0; m < 8; ++m)
                #pragma unroll
                for (int r = 0; r < 4; ++r)
                    *(bf16_t*)(ep + (m * 16 + crow + r) * 128 + (n * 16 + ccol) * 2)
                        = (bf16_t)(acc[m][n][r] + bv);
        }
        LGKM0();
        bf16_t* cb = (bf16_t*)Cout;
        #pragma unroll
        for (int pass = 0; pass < 16; ++pass) {
            const int rloc = pass * 8 + (lane >> 3);
            const int ch   = lane & 7;
            bf16x8 v = *(const bf16x8*)(ep + rloc * 128 + ch * 16);
            *(bf16x8*)((char*)(cb + (bm + wr * 128 + rloc) * (size_t)N + bn + wc * 64) + ch * 16) = v;
        }
    } else {
        #pragma unroll
        for (int n = 0; n < 4; ++n) {
            const size_t col = bn + wc * 64 + n * 16 + ccol;
            float bv = 0.f;
            if constexpr (BIAS) bv = bias[col];
            #pragma unroll
            for (int m = 0; m < 8; ++m) {
                #pragma unroll
                for (int r = 0; r < 4; ++r) {
                    const size_t row = bm + wr * 128 + m * 16 + crow + r;
                    ((float*)Cout)[row * N + col] = acc[m][n][r] + bv;
                }
            }
        }
    }
}

// ---------------------------------------------------------------- attention (R6 verbatim)
__global__ __launch_bounds__(256) void attn_kernel(
    const bf16_t* __restrict__ qkv, bf16_t* __restrict__ outp)
{
    __shared__ bf16_t Ks[128 * 64];
    __shared__ bf16_t Vt[64 * 128];
    __shared__ bf16_t Ps[128 * 128];

    const int h    = blockIdx.x;
    const int b    = blockIdx.y;
    const int tid  = threadIdx.x;
    const int lane = tid & 63;
    const int wave = tid >> 6;

    const bf16_t* base = qkv + (size_t)b * T_SZ * NQKV + h * D_SZ;

    #pragma unroll
    for (int p = 0; p < 4; ++p) {
        int e   = p * 256 + tid;
        int row = e >> 3;
        int col = (e & 7) * 8;
        int4 kv = *reinterpret_cast<const int4*>(base + (size_t)row * NQKV + C_SZ + col);
        int kb = row * 128 + ((col * 2) ^ ((row & 7) << 4));
        *reinterpret_cast<int4*>((char*)Ks + kb) = kv;

        bf16x8 vv = *reinterpret_cast<const bf16x8*>(base + (size_t)row * NQKV + 2 * C_SZ + col);
        #pragma unroll
        for (int j = 0; j < 8; ++j) {
            int d  = col + j;
            int vb = d * 256 + ((row * 2) ^ ((d & 7) << 4));
            *reinterpret_cast<bf16_t*>((char*)Vt + vb) = vv[j];
        }
    }

    bf16x8 qf[2][2];
    #pragma unroll
    for (int mi = 0; mi < 2; ++mi)
        #pragma unroll
        for (int ks = 0; ks < 2; ++ks) {
            int m = wave * 32 + mi * 16 + (lane & 15);
            int d = ks * 32 + (lane >> 4) * 8;
            qf[mi][ks] = *reinterpret_cast<const bf16x8*>(base + (size_t)m * NQKV + d);
        }

    __syncthreads();

    f32x4 s[2][8] = {};
    #pragma unroll
    for (int ks = 0; ks < 2; ++ks) {
        int koff = ks * 32 + (lane >> 4) * 8;
        #pragma unroll
        for (int nj = 0; nj < 8; ++nj) {
            int n  = nj * 16 + (lane & 15);
            int kb = n * 128 + ((koff * 2) ^ ((n & 7) << 4));
            bf16x8 kf = *reinterpret_cast<const bf16x8*>((char*)Ks + kb);
            #pragma unroll
            for (int mi = 0; mi < 2; ++mi)
                s[mi][nj] = __builtin_amdgcn_mfma_f32_16x16x32_bf16(
                    qf[mi][ks], kf, s[mi][nj], 0, 0, 0);
        }
    }

    const float scale = 0.125f;
    #pragma unroll
    for (int mi = 0; mi < 2; ++mi) {
        #pragma unroll
        for (int r = 0; r < 4; ++r) {
            int m = wave * 32 + mi * 16 + ((lane >> 4) << 2) + r;
            float sv[8];
            float mx = -3.0e38f;
            #pragma unroll
            for (int nj = 0; nj < 8; ++nj) {
                int n   = nj * 16 + (lane & 15);
                float v = s[mi][nj][r] * scale;
                v = (n <= m) ? v : -3.0e38f;
                sv[nj] = v;
                mx = fmaxf(mx, v);
            }
            #pragma unroll
            for (int off = 1; off < 16; off <<= 1)
                mx = fmaxf(mx, __shfl_xor(mx, off));
            float sum = 0.f;
            #pragma unroll
            for (int nj = 0; nj < 8; ++nj) {
                float p = __expf(sv[nj] - mx);
                sv[nj] = p;
                sum += p;
            }
            #pragma unroll
            for (int off = 1; off < 16; off <<= 1)
                sum += __shfl_xor(sum, off);
            float inv = 1.0f / sum;
            #pragma unroll
            for (int nj = 0; nj < 8; ++nj) {
                int n  = nj * 16 + (lane & 15);
                int pb = m * 256 + ((n * 2) ^ ((m & 7) << 4));
                *reinterpret_cast<bf16_t*>((char*)Ps + pb) = (bf16_t)(sv[nj] * inv);
            }
        }
    }

    __syncthreads();

    f32x4 o[2][4] = {};
    #pragma unroll
    for (int ks = 0; ks < 4; ++ks) {
        int soff = ks * 32 + (lane >> 4) * 8;
        bf16x8 pf[2];
        #pragma unroll
        for (int mi = 0; mi < 2; ++mi) {
            int m  = wave * 32 + mi * 16 + (lane & 15);
            int pb = m * 256 + ((soff * 2) ^ ((m & 7) << 4));
            pf[mi] = *reinterpret_cast<const bf16x8*>((char*)Ps + pb);
        }
        #pragma unroll
        for (int nj = 0; nj < 4; ++nj) {
            int d  = nj * 16 + (lane & 15);
            int vb = d * 256 + ((soff * 2) ^ ((d & 7) << 4));
            bf16x8 vf = *reinterpret_cast<const bf16x8*>((char*)Vt + vb);
            #pragma unroll
            for (int mi = 0; mi < 2; ++mi)
                o[mi][nj] = __builtin_amdgcn_mfma_f32_16x16x32_bf16(
                    pf[mi], vf, o[mi][nj], 0, 0, 0);
        }
    }

    __syncthreads();

    char* on = (char*)Ps;
    #pragma unroll
    for (int mi = 0; mi < 2; ++mi)
        #pragma unroll
        for (int nj = 0; nj < 4; ++nj)
            #pragma unroll
            for (int r = 0; r < 4; ++r) {
                int m = wave * 32 + mi * 16 + ((lane >> 4) << 2) + r;
                int d = nj * 16 + (lane & 15);
                *(bf16_t*)(on + m * 128 + d * 2) = (bf16_t)o[mi][nj][r];
            }

    __syncthreads();

    bf16_t* op = outp + (size_t)b * T_SZ * C_SZ + h * D_SZ;
    #pragma unroll
    for (int pass = 0; pass < 4; ++pass) {
        int row = pass * 32 + (tid >> 3);
        int ch  = tid & 7;
        bf16x8 v = *(const bf16x8*)(on + row * 128 + ch * 16);
        *(bf16x8*)((char*)(op + (size_t)row * C_SZ) + ch * 16) = v;
    }
}

// ---------------------------------------------------------------- launch
extern "C" void kernel_launch(void* const* d_in, const int* in_sizes, int n_in,
                              void* d_out, int out_size, void* d_ws, size_t ws_size,
                              hipStream_t stream)
{
    const float* x      = (const float*)d_in[0];
    const float* w_qkv  = (const float*)d_in[1];
    const float* w_proj = (const float*)d_in[2];
    const float* b_proj = (const float*)d_in[3];

    const int n_wqkv  = NQKV * C_SZ;        // 1769472
    const int n_wproj = C_SZ * C_SZ;        // 589824

    char* ws = (char*)d_ws;
    bf16_t* wqkvb  = (bf16_t*)ws;
    bf16_t* wprojb = (bf16_t*)(ws + (size_t)n_wqkv * 2);
    bf16_t* qkvb   = (bf16_t*)(ws + (size_t)n_wqkv * 2 + (size_t)n_wproj * 2);     // 302 MB
    bf16_t* attnb  = (bf16_t*)(ws + (size_t)n_wqkv * 2 + (size_t)n_wproj * 2
                                  + (size_t)M_SZ * NQKV * 2);                       // 100 MB

    cvt_f32_bf16<<<(n_wqkv / 8 + 255) / 256, 256, 0, stream>>>(w_qkv, wqkvb, n_wqkv);
    cvt_f32_bf16<<<(n_wproj / 8 + 255) / 256, 256, 0, stream>>>(w_proj, wprojb, n_wproj);

    gemm1_f32a<<<dim3((NQKV / 256) * (M_SZ / 256)), 512, 0, stream>>>(
        x, wqkvb, qkvb, M_SZ, NQKV, C_SZ, NQKV / 256);

    attn_kernel<<<dim3(H_SZ, B_SZ), 256, 0, stream>>>(qkvb, attnb);

    gemm256<false, true><<<dim3((C_SZ / 256) * (M_SZ / 256)), 512, 0, stream>>>(
        attnb, wprojb, d_out, b_proj, M_SZ, C_SZ, C_SZ, C_SZ / 256);
}

// Round 11
// 889.757 us; speedup vs baseline: 1.0001x; 1.0001x over previous
//
#include <hip/hip_runtime.h>
#include <hip/hip_bf16.h>

typedef __bf16 bf16_t;
typedef __attribute__((ext_vector_type(8))) __bf16 bf16x8;
typedef __attribute__((ext_vector_type(4))) float f32x4;

#define B_SZ 512
#define T_SZ 128
#define C_SZ 768
#define H_SZ 12
#define D_SZ 64
#define M_SZ (B_SZ * T_SZ)      // 65536
#define NQKV (3 * C_SZ)          // 2304

// ---------------------------------------------------------------- convert (weights only now)
__global__ __launch_bounds__(256) void cvt_f32_bf16(
    const float* __restrict__ in, bf16_t* __restrict__ out, int n)
{
    int i = (blockIdx.x * blockDim.x + threadIdx.x) * 8;
    int stride = gridDim.x * blockDim.x * 8;
    for (; i < n; i += stride) {
        float4 a = *reinterpret_cast<const float4*>(in + i);
        float4 b = *reinterpret_cast<const float4*>(in + i + 4);
        bf16x8 o;
        o[0] = (bf16_t)a.x; o[1] = (bf16_t)a.y;
        o[2] = (bf16_t)a.z; o[3] = (bf16_t)a.w;
        o[4] = (bf16_t)b.x; o[5] = (bf16_t)b.y;
        o[6] = (bf16_t)b.z; o[7] = (bf16_t)b.w;
        *reinterpret_cast<bf16x8*>(out + i) = o;
    }
}

// ---------------------------------------------------------------- shared GEMM machinery
__device__ __forceinline__ void gload16(const bf16_t* g, const char* l)
{
    __builtin_amdgcn_global_load_lds(
        (const __attribute__((address_space(1))) void*)g,
        (__attribute__((address_space(3))) void*)l, 16, 0, 0);
}

#define BAR() do { asm volatile("" ::: "memory"); \
                   __builtin_amdgcn_s_barrier(); \
                   asm volatile("" ::: "memory"); } while (0)

#define VMC(n) asm volatile("s_waitcnt vmcnt(" #n ")" ::: "memory")

#define LGKMW() asm volatile("s_waitcnt lgkmcnt(0)" ::: "memory")

#define LGKM0() do { asm volatile("s_waitcnt lgkmcnt(0)" ::: "memory"); \
                     __builtin_amdgcn_sched_barrier(0); } while (0)

// register fragment loads (ds_read_b128; compiler schedules lgkm waits)
#define RD_A0(bb) do { _Pragma("unroll") for (int m_ = 0; m_ < 4; ++m_) { \
    af0[m_][0] = *(const bf16x8*)(rdAk0 + (bb)*32768 + m_*2048); \
    af0[m_][1] = *(const bf16x8*)(rdAk1 + (bb)*32768 + m_*2048); } } while (0)

#define RD_AY(bb) do { _Pragma("unroll") for (int m_ = 0; m_ < 4; ++m_) { \
    afY[m_][0] = *(const bf16x8*)(rdAk0 + (bb)*32768 + 8192 + m_*2048); \
    afY[m_][1] = *(const bf16x8*)(rdAk1 + (bb)*32768 + 8192 + m_*2048); } } while (0)

#define RD_B01(bb) do { _Pragma("unroll") for (int n_ = 0; n_ < 2; ++n_) { \
    b01[n_][0] = *(const bf16x8*)(rdBk0 + (bb)*32768 + n_*2048); \
    b01[n_][1] = *(const bf16x8*)(rdBk1 + (bb)*32768 + n_*2048); } } while (0)

#define RD_B23(bb) do { _Pragma("unroll") for (int n_ = 0; n_ < 2; ++n_) { \
    b23[n_][0] = *(const bf16x8*)(rdBk0 + (bb)*32768 + 4096 + n_*2048); \
    b23[n_][1] = *(const bf16x8*)(rdBk1 + (bb)*32768 + 4096 + n_*2048); } } while (0)

// stage half-tile hf of K-tile u into buffer bb (predicated on u < nt)
#define ST_A(bb, hf, u) do { if ((u) < nt) { \
    const bf16_t* s_ = pA + (size_t)((hf)*128) * K + (size_t)(u)*64; \
    char* d_ = ldsAw + (bb)*32768 + (hf)*16384; \
    gload16(s_, d_); gload16(s_ + (size_t)8*K, d_ + 1024); } } while (0)

#define ST_B(bb, hf, u) do { if ((u) < nt) { \
    const bf16_t* s_ = pB + (size_t)((hf)*128) * K + (size_t)(u)*64; \
    char* d_ = ldsBw + (bb)*32768 + (hf)*16384; \
    gload16(s_, d_); gload16(s_ + (size_t)8*K, d_ + 1024); } } while (0)

// quadrant: 16 MFMA on (A_, B_) into acc[mo..mo+3][no..no+1]
#define MFQ(A_, B_, mo, no) do { __builtin_amdgcn_s_setprio(1); \
    _Pragma("unroll") for (int m_ = 0; m_ < 4; ++m_) \
    _Pragma("unroll") for (int n_ = 0; n_ < 2; ++n_) { \
        acc[(mo)+m_][(no)+n_] = __builtin_amdgcn_mfma_f32_16x16x32_bf16( \
            A_[m_][0], B_[n_][0], acc[(mo)+m_][(no)+n_], 0, 0, 0); \
        acc[(mo)+m_][(no)+n_] = __builtin_amdgcn_mfma_f32_16x16x32_bf16( \
            A_[m_][1], B_[n_][1], acc[(mo)+m_][(no)+n_], 0, 0, 0); } \
    __builtin_amdgcn_s_setprio(0); } while (0)

// A f32 reg-staging: thread covers rows w*32 + r8 + 8j (j=0..3), 32 B f32 per row
#define ALOAD(u) do { if ((u) < nt) { \
    const float* s_ = pAf + (size_t)(u) * 64; \
    _Pragma("unroll") for (int j_ = 0; j_ < 4; ++j_) { \
        av[j_*2]   = *(const float4*)(s_ + (size_t)(8*j_) * K); \
        av[j_*2+1] = *(const float4*)(s_ + (size_t)(8*j_) * K + 4); } } } while (0)

#define AWRITE(u, bb) do { if ((u) < nt) { \
    _Pragma("unroll") for (int j_ = 0; j_ < 4; ++j_) { \
        bf16x8 o_; \
        o_[0] = (bf16_t)av[j_*2].x;   o_[1] = (bf16_t)av[j_*2].y; \
        o_[2] = (bf16_t)av[j_*2].z;   o_[3] = (bf16_t)av[j_*2].w; \
        o_[4] = (bf16_t)av[j_*2+1].x; o_[5] = (bf16_t)av[j_*2+1].y; \
        o_[6] = (bf16_t)av[j_*2+1].z; o_[7] = (bf16_t)av[j_*2+1].w; \
        *(bf16x8*)(ldsAwr + (bb)*32768 + j_*1024) = o_; } } } while (0)

// ---------------------------------------------------------------- GEMM1: A f32 fused-convert
// C[M,N](bf16) = cvt_bf16(A_f32[M,K]) * Bt[N,K]^T ; 256x256 tile, BK=64, 8 waves
// launch_bounds(512, 1): occupancy is LDS-bound at 1 block/CU anyway; the
// (512,2) cap at 128 VGPRs caused av[] to spill to scratch (R10: 879 MB WRITE).
__global__ __launch_bounds__(512, 1) void gemm1_f32a(
    const float* __restrict__ A, const bf16_t* __restrict__ Bt,
    bf16_t* __restrict__ Cout, int M, int N, int K, int nx)
{
    __shared__ char smem[131072];   // A: [buf][half][128][64]bf16 @0, B same @65536

    const int tid  = threadIdx.x;
    const int lane = tid & 63;
    const int w    = tid >> 6;
    const int wr   = w >> 2;
    const int wc   = w & 3;

    const int nwg = gridDim.x;
    int bid = blockIdx.x;
    if ((nwg & 7) == 0) bid = (bid & 7) * (nwg >> 3) + (bid >> 3);
    const int bx = bid % nx;
    const int by = bid / nx;
    const size_t bm = (size_t)by * 256;
    const size_t bn = (size_t)bx * 256;

    const int nt    = K >> 6;
    const int niter = nt >> 1;

    // ---- B staging (pre-swizzled global source, linear LDS dest)
    const int i3    = lane >> 3;
    const int colSw = ((lane & 7) ^ i3) * 8;
    const bf16_t* pB = Bt + (bn + (size_t)(w * 16 + i3)) * K + colSw;
    char* ldsBw = smem + 65536 + w * 2048;

    // ---- A staging (f32 global -> regs -> cvt -> swizzled ds_write)
    const int s8 = lane & 7;       // 16-B bf16 slot (= 32-B f32 chunk)
    const int r8 = lane >> 3;      // row&7 for this lane (constant across j)
    const float* pAf = A + (bm + (size_t)(w * 32 + r8)) * K + s8 * 8;
    char* ldsAwr = smem + (w >> 2) * 16384 + ((w & 3) * 32 + r8) * 128 + ((s8 ^ r8) * 16);

    // ---- read addresses (swizzle on read: byte ^= (row&7)<<4) — identical to R6
    const int lane_lo = lane & 15;
    const int sxr  = (lane & 7) << 4;
    const int cK0  = (((lane >> 4) * 16) ^ sxr);
    const int cK1  = cK0 ^ 64;
    const char* rdAk0 = smem + wr * 16384 + lane_lo * 128 + cK0;
    const char* rdAk1 = smem + wr * 16384 + lane_lo * 128 + cK1;
    const char* rdBk0 = smem + 65536 + (wc >> 1) * 16384 + ((wc & 1) * 64 + lane_lo) * 128 + cK0;
    const char* rdBk1 = smem + 65536 + (wc >> 1) * 16384 + ((wc & 1) * 64 + lane_lo) * 128 + cK1;

    f32x4  acc[8][4] = {};
    bf16x8 af0[4][2], afY[4][2], b01[2][2], b23[2][2];
    float4 av[8];

    // ---- prologue: tile0 A (regs->LDS) + B (gload); tile1 A-loads in flight
    ALOAD(0); AWRITE(0, 0);
    ST_B(0, 0, 0); ST_B(0, 1, 0);
    ALOAD(1);
    VMC(8);     // drain the 4 B-gloads (oldest); 8 A-loads stay in flight
    LGKMW();    // A ds_writes landed before barrier
    BAR();

    for (int it = 0; it < niter; ++it) {
        const int u = it * 2;
        const bool lastit = (it + 1 == niter);
        // ---- tile u (buf0); stage tile u+1 -> buf1 only (no mid-barrier needed)
        ST_B(1, 0, u + 1); ST_B(1, 1, u + 1);
        AWRITE(u + 1, 1);          // consumes av(u+1) [older than the STBs -> partial waits]
        ALOAD(u + 2);              // reuse av regs for next tile
        RD_A0(0); RD_B01(0); RD_B23(0); RD_AY(0);
        MFQ(af0, b01, 0, 0); MFQ(af0, b23, 0, 2);
        MFQ(afY, b01, 4, 0); MFQ(afY, b23, 4, 2);
        if (lastit) { VMC(0); } else { VMC(8); }   // drain B(u+1); A(u+2) stays
        LGKMW(); BAR();
        // ---- tile u+1 (buf1); stage tile u+2 -> buf0
        ST_B(0, 0, u + 2); ST_B(0, 1, u + 2);
        AWRITE(u + 2, 0);
        ALOAD(u + 3);
        RD_A0(1); RD_B01(1); RD_B23(1); RD_AY(1);
        MFQ(af0, b01, 0, 0); MFQ(af0, b23, 0, 2);
        MFQ(afY, b01, 4, 0); MFQ(afY, b23, 4, 2);
        if (lastit) { VMC(0); } else { VMC(8); }
        LGKMW(); BAR();
    }

    // ---- epilogue via LDS (R6): scalar ds_writes -> coalesced bf16x8 stores
    const int crow = (lane >> 4) * 4;
    const int ccol = lane & 15;
    char* ep = smem + w * 16384;
    #pragma unroll
    for (int n = 0; n < 4; ++n) {
        #pragma unroll
        for (int m = 0; m < 8; ++m)
            #pragma unroll
            for (int r = 0; r < 4; ++r)
                *(bf16_t*)(ep + (m * 16 + crow + r) * 128 + (n * 16 + ccol) * 2)
                    = (bf16_t)acc[m][n][r];
    }
    LGKM0();
    #pragma unroll
    for (int pass = 0; pass < 16; ++pass) {
        const int rloc = pass * 8 + (lane >> 3);
        const int ch   = lane & 7;
        bf16x8 v = *(const bf16x8*)(ep + rloc * 128 + ch * 16);
        *(bf16x8*)((char*)(Cout + (bm + wr * 128 + rloc) * (size_t)N + bn + wc * 64) + ch * 16) = v;
    }
}

// ---------------------------------------------------------------- GEMM (bf16 A) — R6 verbatim
template <bool BF16_OUT, bool BIAS>
__global__ __launch_bounds__(512, 2) void gemm256(
    const bf16_t* __restrict__ A, const bf16_t* __restrict__ Bt,
    void* __restrict__ Cout, const float* __restrict__ bias,
    int M, int N, int K, int nx)
{
    __shared__ char smem[131072];

    const int tid  = threadIdx.x;
    const int lane = tid & 63;
    const int w    = tid >> 6;
    const int wr   = w >> 2;
    const int wc   = w & 3;

    const int nwg = gridDim.x;
    int bid = blockIdx.x;
    if ((nwg & 7) == 0) bid = (bid & 7) * (nwg >> 3) + (bid >> 3);
    const int bx = bid % nx;
    const int by = bid / nx;
    const size_t bm = (size_t)by * 256;
    const size_t bn = (size_t)bx * 256;

    const int nt    = K >> 6;
    const int niter = nt >> 1;

    const int i3    = lane >> 3;
    const int colSw = ((lane & 7) ^ i3) * 8;
    const bf16_t* pA = A  + (bm + (size_t)(w * 16 + i3)) * K + colSw;
    const bf16_t* pB = Bt + (bn + (size_t)(w * 16 + i3)) * K + colSw;
    char* ldsAw = smem + w * 2048;
    char* ldsBw = smem + 65536 + w * 2048;

    const int lane_lo = lane & 15;
    const int sxr  = (lane & 7) << 4;
    const int cK0  = (((lane >> 4) * 16) ^ sxr);
    const int cK1  = cK0 ^ 64;
    const char* rdAk0 = smem + wr * 16384 + lane_lo * 128 + cK0;
    const char* rdAk1 = smem + wr * 16384 + lane_lo * 128 + cK1;
    const char* rdBk0 = smem + 65536 + (wc >> 1) * 16384 + ((wc & 1) * 64 + lane_lo) * 128 + cK0;
    const char* rdBk1 = smem + 65536 + (wc >> 1) * 16384 + ((wc & 1) * 64 + lane_lo) * 128 + cK1;

    f32x4  acc[8][4] = {};
    bf16x8 af0[4][2], afY[4][2], b01[2][2], b23[2][2];

    ST_B(0, 0, 0); ST_A(0, 0, 0); ST_A(0, 1, 0); ST_B(0, 1, 0);
    ST_B(1, 0, 1); ST_A(1, 0, 1);
    VMC(4);
    BAR();

    for (int it = 0; it < niter; ++it) {
        const int u = it * 2;
        const bool last = (it + 1 == niter);
        RD_A0(0); RD_B01(0); RD_B23(0); ST_A(1, 1, u + 1); MFQ(af0, b01, 0, 0); BAR();
        RD_AY(0);                        ST_B(1, 1, u + 1); MFQ(af0, b23, 0, 2); BAR();
                                         ST_B(0, 0, u + 2); MFQ(afY, b01, 4, 0); BAR();
                                         ST_A(0, 0, u + 2); MFQ(afY, b23, 4, 2);
        if (last) { VMC(0); } else { VMC(4); }
        BAR();
        RD_A0(1); RD_B01(1); RD_B23(1); ST_A(0, 1, u + 2); MFQ(af0, b01, 0, 0); BAR();
        RD_AY(1);                        ST_B(0, 1, u + 2); MFQ(af0, b23, 0, 2); BAR();
                                         ST_B(1, 0, u + 3); MFQ(afY, b01, 4, 0); BAR();
                                         ST_A(1, 0, u + 3); MFQ(afY, b23, 4, 2);
        if (last) { VMC(0); } else { VMC(4); }
        BAR();
    }

    const int crow = (lane >> 4) * 4;
    const int ccol = lane & 15;
    if constexpr (BF16_OUT) {
        char* ep = smem + w * 16384;
        #pragma unroll
        for (int n = 0; n < 4; ++n) {
            const size_t col = bn + wc * 64 + n * 16 + ccol;
            float bv = 0.f;
            if constexpr (BIAS) bv = bias[col];
            #pragma unroll
            for (int m = 0; m < 8; ++m)
                #pragma unroll
                for (int r = 0; r < 4; ++r)
                    *(bf16_t*)(ep + (m * 16 + crow + r) * 128 + (n * 16 + ccol) * 2)
                        = (bf16_t)(acc[m][n][r] + bv);
        }
        LGKM0();
        bf16_t* cb = (bf16_t*)Cout;
        #pragma unroll
        for (int pass = 0; pass < 16; ++pass) {
            const int rloc = pass * 8 + (lane >> 3);
            const int ch   = lane & 7;
            bf16x8 v = *(const bf16x8*)(ep + rloc * 128 + ch * 16);
            *(bf16x8*)((char*)(cb + (bm + wr * 128 + rloc) * (size_t)N + bn + wc * 64) + ch * 16) = v;
        }
    } else {
        #pragma unroll
        for (int n = 0; n < 4; ++n) {
            const size_t col = bn + wc * 64 + n * 16 + ccol;
            float bv = 0.f;
            if constexpr (BIAS) bv = bias[col];
            #pragma unroll
            for (int m = 0; m < 8; ++m) {
                #pragma unroll
                for (int r = 0; r < 4; ++r) {
                    const size_t row = bm + wr * 128 + m * 16 + crow + r;
                    ((float*)Cout)[row * N + col] = acc[m][n][r] + bv;
                }
            }
        }
    }
}

// ---------------------------------------------------------------- attention (R6 verbatim)
__global__ __launch_bounds__(256) void attn_kernel(
    const bf16_t* __restrict__ qkv, bf16_t* __restrict__ outp)
{
    __shared__ bf16_t Ks[128 * 64];
    __shared__ bf16_t Vt[64 * 128];
    __shared__ bf16_t Ps[128 * 128];

    const int h    = blockIdx.x;
    const int b    = blockIdx.y;
    const int tid  = threadIdx.x;
    const int lane = tid & 63;
    const int wave = tid >> 6;

    const bf16_t* base = qkv + (size_t)b * T_SZ * NQKV + h * D_SZ;

    #pragma unroll
    for (int p = 0; p < 4; ++p) {
        int e   = p * 256 + tid;
        int row = e >> 3;
        int col = (e & 7) * 8;
        int4 kv = *reinterpret_cast<const int4*>(base + (size_t)row * NQKV + C_SZ + col);
        int kb = row * 128 + ((col * 2) ^ ((row & 7) << 4));
        *reinterpret_cast<int4*>((char*)Ks + kb) = kv;

        bf16x8 vv = *reinterpret_cast<const bf16x8*>(base + (size_t)row * NQKV + 2 * C_SZ + col);
        #pragma unroll
        for (int j = 0; j < 8; ++j) {
            int d  = col + j;
            int vb = d * 256 + ((row * 2) ^ ((d & 7) << 4));
            *reinterpret_cast<bf16_t*>((char*)Vt + vb) = vv[j];
        }
    }

    bf16x8 qf[2][2];
    #pragma unroll
    for (int mi = 0; mi < 2; ++mi)
        #pragma unroll
        for (int ks = 0; ks < 2; ++ks) {
            int m = wave * 32 + mi * 16 + (lane & 15);
            int d = ks * 32 + (lane >> 4) * 8;
            qf[mi][ks] = *reinterpret_cast<const bf16x8*>(base + (size_t)m * NQKV + d);
        }

    __syncthreads();

    f32x4 s[2][8] = {};
    #pragma unroll
    for (int ks = 0; ks < 2; ++ks) {
        int koff = ks * 32 + (lane >> 4) * 8;
        #pragma unroll
        for (int nj = 0; nj < 8; ++nj) {
            int n  = nj * 16 + (lane & 15);
            int kb = n * 128 + ((koff * 2) ^ ((n & 7) << 4));
            bf16x8 kf = *reinterpret_cast<const bf16x8*>((char*)Ks + kb);
            #pragma unroll
            for (int mi = 0; mi < 2; ++mi)
                s[mi][nj] = __builtin_amdgcn_mfma_f32_16x16x32_bf16(
                    qf[mi][ks], kf, s[mi][nj], 0, 0, 0);
        }
    }

    const float scale = 0.125f;
    #pragma unroll
    for (int mi = 0; mi < 2; ++mi) {
        #pragma unroll
        for (int r = 0; r < 4; ++r) {
            int m = wave * 32 + mi * 16 + ((lane >> 4) << 2) + r;
            float sv[8];
            float mx = -3.0e38f;
            #pragma unroll
            for (int nj = 0; nj < 8; ++nj) {
                int n   = nj * 16 + (lane & 15);
                float v = s[mi][nj][r] * scale;
                v = (n <= m) ? v : -3.0e38f;
                sv[nj] = v;
                mx = fmaxf(mx, v);
            }
            #pragma unroll
            for (int off = 1; off < 16; off <<= 1)
                mx = fmaxf(mx, __shfl_xor(mx, off));
            float sum = 0.f;
            #pragma unroll
            for (int nj = 0; nj < 8; ++nj) {
                float p = __expf(sv[nj] - mx);
                sv[nj] = p;
                sum += p;
            }
            #pragma unroll
            for (int off = 1; off < 16; off <<= 1)
                sum += __shfl_xor(sum, off);
            float inv = 1.0f / sum;
            #pragma unroll
            for (int nj = 0; nj < 8; ++nj) {
                int n  = nj * 16 + (lane & 15);
                int pb = m * 256 + ((n * 2) ^ ((m & 7) << 4));
                *reinterpret_cast<bf16_t*>((char*)Ps + pb) = (bf16_t)(sv[nj] * inv);
            }
        }
    }

    __syncthreads();

    f32x4 o[2][4] = {};
    #pragma unroll
    for (int ks = 0; ks < 4; ++ks) {
        int soff = ks * 32 + (lane >> 4) * 8;
        bf16x8 pf[2];
        #pragma unroll
        for (int mi = 0; mi < 2; ++mi) {
            int m  = wave * 32 + mi * 16 + (lane & 15);
            int pb = m * 256 + ((soff * 2) ^ ((m & 7) << 4));
            pf[mi] = *reinterpret_cast<const bf16x8*>((char*)Ps + pb);
        }
        #pragma unroll
        for (int nj = 0; nj < 4; ++nj) {
            int d  = nj * 16 + (lane & 15);
            int vb = d * 256 + ((soff * 2) ^ ((d & 7) << 4));
            bf16x8 vf = *reinterpret_cast<const bf16x8*>((char*)Vt + vb);
            #pragma unroll
            for (int mi = 0; mi < 2; ++mi)
                o[mi][nj] = __builtin_amdgcn_mfma_f32_16x16x32_bf16(
                    pf[mi], vf, o[mi][nj], 0, 0, 0);
        }
    }

    __syncthreads();

    char* on = (char*)Ps;
    #pragma unroll
    for (int mi = 0; mi < 2; ++mi)
        #pragma unroll
        for (int nj = 0; nj < 4; ++nj)
            #pragma unroll
            for (int r = 0; r < 4; ++r) {
                int m = wave * 32 + mi * 16 + ((lane >> 4) << 2) + r;
                int d = nj * 16 + (lane & 15);
                *(bf16_t*)(on + m * 128 + d * 2) = (bf16_t)o[mi][nj][r];
            }

    __syncthreads();

    bf16_t* op = outp + (size_t)b * T_SZ * C_SZ + h * D_SZ;
    #pragma unroll
    for (int pass = 0; pass < 4; ++pass) {
        int row = pass * 32 + (tid >> 3);
        int ch  = tid & 7;
        bf16x8 v = *(const bf16x8*)(on + row * 128 + ch * 16);
        *(bf16x8*)((char*)(op + (size_t)row * C_SZ) + ch * 16) = v;
    }
}

// ---------------------------------------------------------------- launch
extern "C" void kernel_launch(void* const* d_in, const int* in_sizes, int n_in,
                              void* d_out, int out_size, void* d_ws, size_t ws_size,
                              hipStream_t stream)
{
    const float* x      = (const float*)d_in[0];
    const float* w_qkv  = (const float*)d_in[1];
    const float* w_proj = (const float*)d_in[2];
    const float* b_proj = (const float*)d_in[3];

    const int n_wqkv  = NQKV * C_SZ;        // 1769472
    const int n_wproj = C_SZ * C_SZ;        // 589824

    char* ws = (char*)d_ws;
    bf16_t* wqkvb  = (bf16_t*)ws;
    bf16_t* wprojb = (bf16_t*)(ws + (size_t)n_wqkv * 2);
    bf16_t* qkvb   = (bf16_t*)(ws + (size_t)n_wqkv * 2 + (size_t)n_wproj * 2);     // 302 MB
    bf16_t* attnb  = (bf16_t*)(ws + (size_t)n_wqkv * 2 + (size_t)n_wproj * 2
                                  + (size_t)M_SZ * NQKV * 2);                       // 100 MB

    cvt_f32_bf16<<<(n_wqkv / 8 + 255) / 256, 256, 0, stream>>>(w_qkv, wqkvb, n_wqkv);
    cvt_f32_bf16<<<(n_wproj / 8 + 255) / 256, 256, 0, stream>>>(w_proj, wprojb, n_wproj);

    gemm1_f32a<<<dim3((NQKV / 256) * (M_SZ / 256)), 512, 0, stream>>>(
        x, wqkvb, qkvb, M_SZ, NQKV, C_SZ, NQKV / 256);

    attn_kernel<<<dim3(H_SZ, B_SZ), 256, 0, stream>>>(qkvb, attnb);

    gemm256<false, true><<<dim3((C_SZ / 256) * (M_SZ / 256)), 512, 0, stream>>>(
        attnb, wprojb, d_out, b_proj, M_SZ, C_SZ, C_SZ, C_SZ / 256);
}

// Round 12
// 557.013 us; speedup vs baseline: 1.5975x; 1.5974x over previous
//
#include <hip/hip_runtime.h>
#include <hip/hip_bf16.h>

typedef __bf16 bf16_t;
typedef __attribute__((ext_vector_type(8))) __bf16 bf16x8;
typedef __attribute__((ext_vector_type(4))) float f32x4;

#define B_SZ 512
#define T_SZ 128
#define C_SZ 768
#define H_SZ 12
#define D_SZ 64
#define M_SZ (B_SZ * T_SZ)      // 65536
#define NQKV (3 * C_SZ)          // 2304

// ---------------------------------------------------------------- convert (weights only)
__global__ __launch_bounds__(256) void cvt_f32_bf16(
    const float* __restrict__ in, bf16_t* __restrict__ out, int n)
{
    int i = (blockIdx.x * blockDim.x + threadIdx.x) * 8;
    int stride = gridDim.x * blockDim.x * 8;
    for (; i < n; i += stride) {
        float4 a = *reinterpret_cast<const float4*>(in + i);
        float4 b = *reinterpret_cast<const float4*>(in + i + 4);
        bf16x8 o;
        o[0] = (bf16_t)a.x; o[1] = (bf16_t)a.y;
        o[2] = (bf16_t)a.z; o[3] = (bf16_t)a.w;
        o[4] = (bf16_t)b.x; o[5] = (bf16_t)b.y;
        o[6] = (bf16_t)b.z; o[7] = (bf16_t)b.w;
        *reinterpret_cast<bf16x8*>(out + i) = o;
    }
}

// ---------------------------------------------------------------- shared GEMM machinery
__device__ __forceinline__ void gload16(const bf16_t* g, const char* l)
{
    __builtin_amdgcn_global_load_lds(
        (const __attribute__((address_space(1))) void*)g,
        (__attribute__((address_space(3))) void*)l, 16, 0, 0);
}

#define BAR() do { asm volatile("" ::: "memory"); \
                   __builtin_amdgcn_s_barrier(); \
                   asm volatile("" ::: "memory"); } while (0)

#define VMC(n) asm volatile("s_waitcnt vmcnt(" #n ")" ::: "memory")

#define LGKMW() asm volatile("s_waitcnt lgkmcnt(0)" ::: "memory")

#define LGKM0() do { asm volatile("s_waitcnt lgkmcnt(0)" ::: "memory"); \
                     __builtin_amdgcn_sched_barrier(0); } while (0)

// register fragment loads (ds_read_b128)
#define RD_A0(bb) do { _Pragma("unroll") for (int m_ = 0; m_ < 4; ++m_) { \
    af0[m_][0] = *(const bf16x8*)(rdAk0 + (bb)*32768 + m_*2048); \
    af0[m_][1] = *(const bf16x8*)(rdAk1 + (bb)*32768 + m_*2048); } } while (0)

#define RD_AY(bb) do { _Pragma("unroll") for (int m_ = 0; m_ < 4; ++m_) { \
    afY[m_][0] = *(const bf16x8*)(rdAk0 + (bb)*32768 + 8192 + m_*2048); \
    afY[m_][1] = *(const bf16x8*)(rdAk1 + (bb)*32768 + 8192 + m_*2048); } } while (0)

#define RD_B01(bb) do { _Pragma("unroll") for (int n_ = 0; n_ < 2; ++n_) { \
    b01[n_][0] = *(const bf16x8*)(rdBk0 + (bb)*32768 + n_*2048); \
    b01[n_][1] = *(const bf16x8*)(rdBk1 + (bb)*32768 + n_*2048); } } while (0)

#define RD_B23(bb) do { _Pragma("unroll") for (int n_ = 0; n_ < 2; ++n_) { \
    b23[n_][0] = *(const bf16x8*)(rdBk0 + (bb)*32768 + 4096 + n_*2048); \
    b23[n_][1] = *(const bf16x8*)(rdBk1 + (bb)*32768 + 4096 + n_*2048); } } while (0)

#define ST_A(bb, hf, u) do { if ((u) < nt) { \
    const bf16_t* s_ = pA + (size_t)((hf)*128) * K + (size_t)(u)*64; \
    char* d_ = ldsAw + (bb)*32768 + (hf)*16384; \
    gload16(s_, d_); gload16(s_ + (size_t)8*K, d_ + 1024); } } while (0)

#define ST_B(bb, hf, u) do { if ((u) < nt) { \
    const bf16_t* s_ = pB + (size_t)((hf)*128) * K + (size_t)(u)*64; \
    char* d_ = ldsBw + (bb)*32768 + (hf)*16384; \
    gload16(s_, d_); gload16(s_ + (size_t)8*K, d_ + 1024); } } while (0)

#define MFQ(A_, B_, mo, no) do { __builtin_amdgcn_s_setprio(1); \
    _Pragma("unroll") for (int m_ = 0; m_ < 4; ++m_) \
    _Pragma("unroll") for (int n_ = 0; n_ < 2; ++n_) { \
        acc[(mo)+m_][(no)+n_] = __builtin_amdgcn_mfma_f32_16x16x32_bf16( \
            A_[m_][0], B_[n_][0], acc[(mo)+m_][(no)+n_], 0, 0, 0); \
        acc[(mo)+m_][(no)+n_] = __builtin_amdgcn_mfma_f32_16x16x32_bf16( \
            A_[m_][1], B_[n_][1], acc[(mo)+m_][(no)+n_], 0, 0, 0); } \
    __builtin_amdgcn_s_setprio(0); } while (0)

// A f32 reg-staging, HALF h (rows j = 2h, 2h+1): 16 VGPRs live per half
#define ALOAD_H(u, AV, h) do { if ((u) < nt) { \
    const float* s_ = pAf + (size_t)(u) * 64; \
    _Pragma("unroll") for (int q_ = 0; q_ < 2; ++q_) { \
        AV[q_*2]   = *(const float4*)(s_ + (size_t)(8*(2*(h)+q_)) * K); \
        AV[q_*2+1] = *(const float4*)(s_ + (size_t)(8*(2*(h)+q_)) * K + 4); } } } while (0)

#define AWRITE_H(u, bb, AV, h) do { if ((u) < nt) { \
    _Pragma("unroll") for (int q_ = 0; q_ < 2; ++q_) { \
        bf16x8 o_; \
        o_[0] = (bf16_t)AV[q_*2].x;   o_[1] = (bf16_t)AV[q_*2].y; \
        o_[2] = (bf16_t)AV[q_*2].z;   o_[3] = (bf16_t)AV[q_*2].w; \
        o_[4] = (bf16_t)AV[q_*2+1].x; o_[5] = (bf16_t)AV[q_*2+1].y; \
        o_[6] = (bf16_t)AV[q_*2+1].z; o_[7] = (bf16_t)AV[q_*2+1].w; \
        *(bf16x8*)(ldsAwr + (bb)*32768 + (2*(h)+q_)*1024) = o_; } } } while (0)

// A-frag reuse loads (single af[4][2] buffer, halves loaded in sequence)
#define RD_AH0(bb) do { _Pragma("unroll") for (int m_ = 0; m_ < 4; ++m_) { \
    af[m_][0] = *(const bf16x8*)(rdAk0 + (bb)*32768 + m_*2048); \
    af[m_][1] = *(const bf16x8*)(rdAk1 + (bb)*32768 + m_*2048); } } while (0)

#define RD_AH1(bb) do { _Pragma("unroll") for (int m_ = 0; m_ < 4; ++m_) { \
    af[m_][0] = *(const bf16x8*)(rdAk0 + (bb)*32768 + 8192 + m_*2048); \
    af[m_][1] = *(const bf16x8*)(rdAk1 + (bb)*32768 + 8192 + m_*2048); } } while (0)

// ---------------------------------------------------------------- GEMM1: A f32 fused-convert
// Schedule = R10 (correctness verified); register-lean A-path: single af[4][2]
// fragment buffer (reloaded per half) + av split into two 4xfloat4 halves.
// Arch-VGPR budget ~105 <= 128 cap (acc holds 128 AGPRs of the 256/wave file).
__global__ __launch_bounds__(512, 2) void gemm1_f32a(
    const float* __restrict__ A, const bf16_t* __restrict__ Bt,
    bf16_t* __restrict__ Cout, int M, int N, int K, int nx)
{
    __shared__ char smem[131072];

    const int tid  = threadIdx.x;
    const int lane = tid & 63;
    const int w    = tid >> 6;
    const int wr   = w >> 2;
    const int wc   = w & 3;

    const int nwg = gridDim.x;
    int bid = blockIdx.x;
    if ((nwg & 7) == 0) bid = (bid & 7) * (nwg >> 3) + (bid >> 3);
    const int bx = bid % nx;
    const int by = bid / nx;
    const size_t bm = (size_t)by * 256;
    const size_t bn = (size_t)bx * 256;

    const int nt    = K >> 6;
    const int niter = nt >> 1;

    // ---- B staging (pre-swizzled global source, linear LDS dest)
    const int i3    = lane >> 3;
    const int colSw = ((lane & 7) ^ i3) * 8;
    const bf16_t* pB = Bt + (bn + (size_t)(w * 16 + i3)) * K + colSw;
    char* ldsBw = smem + 65536 + w * 2048;

    // ---- A staging (f32 global -> regs -> cvt -> swizzled ds_write)
    const int s8 = lane & 7;
    const int r8 = lane >> 3;
    const float* pAf = A + (bm + (size_t)(w * 32 + r8)) * K + s8 * 8;
    char* ldsAwr = smem + (w >> 2) * 16384 + ((w & 3) * 32 + r8) * 128 + ((s8 ^ r8) * 16);

    // ---- read addresses (swizzle on read: byte ^= (row&7)<<4)
    const int lane_lo = lane & 15;
    const int sxr  = (lane & 7) << 4;
    const int cK0  = (((lane >> 4) * 16) ^ sxr);
    const int cK1  = cK0 ^ 64;
    const char* rdAk0 = smem + wr * 16384 + lane_lo * 128 + cK0;
    const char* rdAk1 = smem + wr * 16384 + lane_lo * 128 + cK1;
    const char* rdBk0 = smem + 65536 + (wc >> 1) * 16384 + ((wc & 1) * 64 + lane_lo) * 128 + cK0;
    const char* rdBk1 = smem + 65536 + (wc >> 1) * 16384 + ((wc & 1) * 64 + lane_lo) * 128 + cK1;

    f32x4  acc[8][4] = {};
    bf16x8 af[4][2], b01[2][2], b23[2][2];
    float4 av0[4], av1[4];

    // ---- prologue: tile0 A (regs->LDS) + B (gload); tile1 A-loads in flight
    ALOAD_H(0, av0, 0); ALOAD_H(0, av1, 1);
    AWRITE_H(0, 0, av0, 0); AWRITE_H(0, 0, av1, 1);
    ST_B(0, 0, 0); ST_B(0, 1, 0);
    ALOAD_H(1, av0, 0); ALOAD_H(1, av1, 1);
    VMC(8);     // drain the 4 B-gloads; 8 A-loads (tile1) stay in flight
    LGKMW();
    BAR();

    for (int it = 0; it < niter; ++it) {
        const int u = it * 2;
        const bool lastit = (it + 1 == niter);
        // ---- tile u (buf0); stage tile u+1 -> buf1
        ST_B(1, 0, u + 1); ST_B(1, 1, u + 1);
        AWRITE_H(u + 1, 1, av0, 0); ALOAD_H(u + 2, av0, 0);
        AWRITE_H(u + 1, 1, av1, 1); ALOAD_H(u + 2, av1, 1);
        RD_AH0(0); RD_B01(0); RD_B23(0);
        MFQ(af, b01, 0, 0); MFQ(af, b23, 0, 2);
        RD_AH1(0);
        MFQ(af, b01, 4, 0); MFQ(af, b23, 4, 2);
        if (lastit) { VMC(0); } else { VMC(8); }
        LGKMW(); BAR();
        // ---- tile u+1 (buf1); stage tile u+2 -> buf0
        ST_B(0, 0, u + 2); ST_B(0, 1, u + 2);
        AWRITE_H(u + 2, 0, av0, 0); ALOAD_H(u + 3, av0, 0);
        AWRITE_H(u + 2, 0, av1, 1); ALOAD_H(u + 3, av1, 1);
        RD_AH0(1); RD_B01(1); RD_B23(1);
        MFQ(af, b01, 0, 0); MFQ(af, b23, 0, 2);
        RD_AH1(1);
        MFQ(af, b01, 4, 0); MFQ(af, b23, 4, 2);
        if (lastit) { VMC(0); } else { VMC(8); }
        LGKMW(); BAR();
    }

    // ---- epilogue via LDS: scalar ds_writes -> coalesced bf16x8 stores
    const int crow = (lane >> 4) * 4;
    const int ccol = lane & 15;
    char* ep = smem + w * 16384;
    #pragma unroll
    for (int n = 0; n < 4; ++n) {
        #pragma unroll
        for (int m = 0; m < 8; ++m)
            #pragma unroll
            for (int r = 0; r < 4; ++r)
                *(bf16_t*)(ep + (m * 16 + crow + r) * 128 + (n * 16 + ccol) * 2)
                    = (bf16_t)acc[m][n][r];
    }
    LGKM0();
    #pragma unroll
    for (int pass = 0; pass < 16; ++pass) {
        const int rloc = pass * 8 + (lane >> 3);
        const int ch   = lane & 7;
        bf16x8 v = *(const bf16x8*)(ep + rloc * 128 + ch * 16);
        *(bf16x8*)((char*)(Cout + (bm + wr * 128 + rloc) * (size_t)N + bn + wc * 64) + ch * 16) = v;
    }
}

// ---------------------------------------------------------------- GEMM (bf16 A) — R6 verbatim
template <bool BF16_OUT, bool BIAS>
__global__ __launch_bounds__(512, 2) void gemm256(
    const bf16_t* __restrict__ A, const bf16_t* __restrict__ Bt,
    void* __restrict__ Cout, const float* __restrict__ bias,
    int M, int N, int K, int nx)
{
    __shared__ char smem[131072];

    const int tid  = threadIdx.x;
    const int lane = tid & 63;
    const int w    = tid >> 6;
    const int wr   = w >> 2;
    const int wc   = w & 3;

    const int nwg = gridDim.x;
    int bid = blockIdx.x;
    if ((nwg & 7) == 0) bid = (bid & 7) * (nwg >> 3) + (bid >> 3);
    const int bx = bid % nx;
    const int by = bid / nx;
    const size_t bm = (size_t)by * 256;
    const size_t bn = (size_t)bx * 256;

    const int nt    = K >> 6;
    const int niter = nt >> 1;

    const int i3    = lane >> 3;
    const int colSw = ((lane & 7) ^ i3) * 8;
    const bf16_t* pA = A  + (bm + (size_t)(w * 16 + i3)) * K + colSw;
    const bf16_t* pB = Bt + (bn + (size_t)(w * 16 + i3)) * K + colSw;
    char* ldsAw = smem + w * 2048;
    char* ldsBw = smem + 65536 + w * 2048;

    const int lane_lo = lane & 15;
    const int sxr  = (lane & 7) << 4;
    const int cK0  = (((lane >> 4) * 16) ^ sxr);
    const int cK1  = cK0 ^ 64;
    const char* rdAk0 = smem + wr * 16384 + lane_lo * 128 + cK0;
    const char* rdAk1 = smem + wr * 16384 + lane_lo * 128 + cK1;
    const char* rdBk0 = smem + 65536 + (wc >> 1) * 16384 + ((wc & 1) * 64 + lane_lo) * 128 + cK0;
    const char* rdBk1 = smem + 65536 + (wc >> 1) * 16384 + ((wc & 1) * 64 + lane_lo) * 128 + cK1;

    f32x4  acc[8][4] = {};
    bf16x8 af0[4][2], afY[4][2], b01[2][2], b23[2][2];

    ST_B(0, 0, 0); ST_A(0, 0, 0); ST_A(0, 1, 0); ST_B(0, 1, 0);
    ST_B(1, 0, 1); ST_A(1, 0, 1);
    VMC(4);
    BAR();

    for (int it = 0; it < niter; ++it) {
        const int u = it * 2;
        const bool last = (it + 1 == niter);
        RD_A0(0); RD_B01(0); RD_B23(0); ST_A(1, 1, u + 1); MFQ(af0, b01, 0, 0); BAR();
        RD_AY(0);                        ST_B(1, 1, u + 1); MFQ(af0, b23, 0, 2); BAR();
                                         ST_B(0, 0, u + 2); MFQ(afY, b01, 4, 0); BAR();
                                         ST_A(0, 0, u + 2); MFQ(afY, b23, 4, 2);
        if (last) { VMC(0); } else { VMC(4); }
        BAR();
        RD_A0(1); RD_B01(1); RD_B23(1); ST_A(0, 1, u + 2); MFQ(af0, b01, 0, 0); BAR();
        RD_AY(1);                        ST_B(0, 1, u + 2); MFQ(af0, b23, 0, 2); BAR();
                                         ST_B(1, 0, u + 3); MFQ(afY, b01, 4, 0); BAR();
                                         ST_A(1, 0, u + 3); MFQ(afY, b23, 4, 2);
        if (last) { VMC(0); } else { VMC(4); }
        BAR();
    }

    const int crow = (lane >> 4) * 4;
    const int ccol = lane & 15;
    if constexpr (BF16_OUT) {
        char* ep = smem + w * 16384;
        #pragma unroll
        for (int n = 0; n < 4; ++n) {
            const size_t col = bn + wc * 64 + n * 16 + ccol;
            float bv = 0.f;
            if constexpr (BIAS) bv = bias[col];
            #pragma unroll
            for (int m = 0; m < 8; ++m)
                #pragma unroll
                for (int r = 0; r < 4; ++r)
                    *(bf16_t*)(ep + (m * 16 + crow + r) * 128 + (n * 16 + ccol) * 2)
                        = (bf16_t)(acc[m][n][r] + bv);
        }
        LGKM0();
        bf16_t* cb = (bf16_t*)Cout;
        #pragma unroll
        for (int pass = 0; pass < 16; ++pass) {
            const int rloc = pass * 8 + (lane >> 3);
            const int ch   = lane & 7;
            bf16x8 v = *(const bf16x8*)(ep + rloc * 128 + ch * 16);
            *(bf16x8*)((char*)(cb + (bm + wr * 128 + rloc) * (size_t)N + bn + wc * 64) + ch * 16) = v;
        }
    } else {
        #pragma unroll
        for (int n = 0; n < 4; ++n) {
            const size_t col = bn + wc * 64 + n * 16 + ccol;
            float bv = 0.f;
            if constexpr (BIAS) bv = bias[col];
            #pragma unroll
            for (int m = 0; m < 8; ++m) {
                #pragma unroll
                for (int r = 0; r < 4; ++r) {
                    const size_t row = bm + wr * 128 + m * 16 + crow + r;
                    ((float*)Cout)[row * N + col] = acc[m][n][r] + bv;
                }
            }
        }
    }
}

// ---------------------------------------------------------------- attention (R6 verbatim)
__global__ __launch_bounds__(256) void attn_kernel(
    const bf16_t* __restrict__ qkv, bf16_t* __restrict__ outp)
{
    __shared__ bf16_t Ks[128 * 64];
    __shared__ bf16_t Vt[64 * 128];
    __shared__ bf16_t Ps[128 * 128];

    const int h    = blockIdx.x;
    const int b    = blockIdx.y;
    const int tid  = threadIdx.x;
    const int lane = tid & 63;
    const int wave = tid >> 6;

    const bf16_t* base = qkv + (size_t)b * T_SZ * NQKV + h * D_SZ;

    #pragma unroll
    for (int p = 0; p < 4; ++p) {
        int e   = p * 256 + tid;
        int row = e >> 3;
        int col = (e & 7) * 8;
        int4 kv = *reinterpret_cast<const int4*>(base + (size_t)row * NQKV + C_SZ + col);
        int kb = row * 128 + ((col * 2) ^ ((row & 7) << 4));
        *reinterpret_cast<int4*>((char*)Ks + kb) = kv;

        bf16x8 vv = *reinterpret_cast<const bf16x8*>(base + (size_t)row * NQKV + 2 * C_SZ + col);
        #pragma unroll
        for (int j = 0; j < 8; ++j) {
            int d  = col + j;
            int vb = d * 256 + ((row * 2) ^ ((d & 7) << 4));
            *reinterpret_cast<bf16_t*>((char*)Vt + vb) = vv[j];
        }
    }

    bf16x8 qf[2][2];
    #pragma unroll
    for (int mi = 0; mi < 2; ++mi)
        #pragma unroll
        for (int ks = 0; ks < 2; ++ks) {
            int m = wave * 32 + mi * 16 + (lane & 15);
            int d = ks * 32 + (lane >> 4) * 8;
            qf[mi][ks] = *reinterpret_cast<const bf16x8*>(base + (size_t)m * NQKV + d);
        }

    __syncthreads();

    f32x4 s[2][8] = {};
    #pragma unroll
    for (int ks = 0; ks < 2; ++ks) {
        int koff = ks * 32 + (lane >> 4) * 8;
        #pragma unroll
        for (int nj = 0; nj < 8; ++nj) {
            int n  = nj * 16 + (lane & 15);
            int kb = n * 128 + ((koff * 2) ^ ((n & 7) << 4));
            bf16x8 kf = *reinterpret_cast<const bf16x8*>((char*)Ks + kb);
            #pragma unroll
            for (int mi = 0; mi < 2; ++mi)
                s[mi][nj] = __builtin_amdgcn_mfma_f32_16x16x32_bf16(
                    qf[mi][ks], kf, s[mi][nj], 0, 0, 0);
        }
    }

    const float scale = 0.125f;
    #pragma unroll
    for (int mi = 0; mi < 2; ++mi) {
        #pragma unroll
        for (int r = 0; r < 4; ++r) {
            int m = wave * 32 + mi * 16 + ((lane >> 4) << 2) + r;
            float sv[8];
            float mx = -3.0e38f;
            #pragma unroll
            for (int nj = 0; nj < 8; ++nj) {
                int n   = nj * 16 + (lane & 15);
                float v = s[mi][nj][r] * scale;
                v = (n <= m) ? v : -3.0e38f;
                sv[nj] = v;
                mx = fmaxf(mx, v);
            }
            #pragma unroll
            for (int off = 1; off < 16; off <<= 1)
                mx = fmaxf(mx, __shfl_xor(mx, off));
            float sum = 0.f;
            #pragma unroll
            for (int nj = 0; nj < 8; ++nj) {
                float p = __expf(sv[nj] - mx);
                sv[nj] = p;
                sum += p;
            }
            #pragma unroll
            for (int off = 1; off < 16; off <<= 1)
                sum += __shfl_xor(sum, off);
            float inv = 1.0f / sum;
            #pragma unroll
            for (int nj = 0; nj < 8; ++nj) {
                int n  = nj * 16 + (lane & 15);
                int pb = m * 256 + ((n * 2) ^ ((m & 7) << 4));
                *reinterpret_cast<bf16_t*>((char*)Ps + pb) = (bf16_t)(sv[nj] * inv);
            }
        }
    }

    __syncthreads();

    f32x4 o[2][4] = {};
    #pragma unroll
    for (int ks = 0; ks < 4; ++ks) {
        int soff = ks * 32 + (lane >> 4) * 8;
        bf16x8 pf[2];
        #pragma unroll
        for (int mi = 0; mi < 2; ++mi) {
            int m  = wave * 32 + mi * 16 + (lane & 15);
            int pb = m * 256 + ((soff * 2) ^ ((m & 7) << 4));
            pf[mi] = *reinterpret_cast<const bf16x8*>((char*)Ps + pb);
        }
        #pragma unroll
        for (int nj = 0; nj < 4; ++nj) {
            int d  = nj * 16 + (lane & 15);
            int vb = d * 256 + ((soff * 2) ^ ((d & 7) << 4));
            bf16x8 vf = *reinterpret_cast<const bf16x8*>((char*)Vt + vb);
            #pragma unroll
            for (int mi = 0; mi < 2; ++mi)
                o[mi][nj] = __builtin_amdgcn_mfma_f32_16x16x32_bf16(
                    pf[mi], vf, o[mi][nj], 0, 0, 0);
        }
    }

    __syncthreads();

    char* on = (char*)Ps;
    #pragma unroll
    for (int mi = 0; mi < 2; ++mi)
        #pragma unroll
        for (int nj = 0; nj < 4; ++nj)
            #pragma unroll
            for (int r = 0; r < 4; ++r) {
                int m = wave * 32 + mi * 16 + ((lane >> 4) << 2) + r;
                int d = nj * 16 + (lane & 15);
                *(bf16_t*)(on + m * 128 + d * 2) = (bf16_t)o[mi][nj][r];
            }

    __syncthreads();

    bf16_t* op = outp + (size_t)b * T_SZ * C_SZ + h * D_SZ;
    #pragma unroll
    for (int pass = 0; pass < 4; ++pass) {
        int row = pass * 32 + (tid >> 3);
        int ch  = tid & 7;
        bf16x8 v = *(const bf16x8*)(on + row * 128 + ch * 16);
        *(bf16x8*)((char*)(op + (size_t)row * C_SZ) + ch * 16) = v;
    }
}

// ---------------------------------------------------------------- launch
extern "C" void kernel_launch(void* const* d_in, const int* in_sizes, int n_in,
                              void* d_out, int out_size, void* d_ws, size_t ws_size,
                              hipStream_t stream)
{
    const float* x      = (const float*)d_in[0];
    const float* w_qkv  = (const float*)d_in[1];
    const float* w_proj = (const float*)d_in[2];
    const float* b_proj = (const float*)d_in[3];

    const int n_wqkv  = NQKV * C_SZ;        // 1769472
    const int n_wproj = C_SZ * C_SZ;        // 589824

    char* ws = (char*)d_ws;
    bf16_t* wqkvb  = (bf16_t*)ws;
    bf16_t* wprojb = (bf16_t*)(ws + (size_t)n_wqkv * 2);
    bf16_t* qkvb   = (bf16_t*)(ws + (size_t)n_wqkv * 2 + (size_t)n_wproj * 2);     // 302 MB
    bf16_t* attnb  = (bf16_t*)(ws + (size_t)n_wqkv * 2 + (size_t)n_wproj * 2
                                  + (size_t)M_SZ * NQKV * 2);                       // 100 MB

    cvt_f32_bf16<<<(n_wqkv / 8 + 255) / 256, 256, 0, stream>>>(w_qkv, wqkvb, n_wqkv);
    cvt_f32_bf16<<<(n_wproj / 8 + 255) / 256, 256, 0, stream>>>(w_proj, wprojb, n_wproj);

    gemm1_f32a<<<dim3((NQKV / 256) * (M_SZ / 256)), 512, 0, stream>>>(
        x, wqkvb, qkvb, M_SZ, NQKV, C_SZ, NQKV / 256);

    attn_kernel<<<dim3(H_SZ, B_SZ), 256, 0, stream>>>(qkvb, attnb);

    gemm256<false, true><<<dim3((C_SZ / 256) * (M_SZ / 256)), 512, 0, stream>>>(
        attnb, wprojb, d_out, b_proj, M_SZ, C_SZ, C_SZ, C_SZ / 256);
}

// Round 13
// 524.181 us; speedup vs baseline: 1.6976x; 1.0626x over previous
//
#include <hip/hip_runtime.h>
#include <hip/hip_bf16.h>

typedef __bf16 bf16_t;
typedef __attribute__((ext_vector_type(8))) __bf16 bf16x8;
typedef __attribute__((ext_vector_type(4))) float f32x4;

#define B_SZ 512
#define T_SZ 128
#define C_SZ 768
#define H_SZ 12
#define D_SZ 64
#define M_SZ (B_SZ * T_SZ)      // 65536
#define NQKV (3 * C_SZ)          // 2304

// ---------------------------------------------------------------- convert
__global__ __launch_bounds__(256) void cvt_f32_bf16(
    const float* __restrict__ in, bf16_t* __restrict__ out, int n)
{
    int i = (blockIdx.x * blockDim.x + threadIdx.x) * 8;
    int stride = gridDim.x * blockDim.x * 8;
    for (; i < n; i += stride) {
        float4 a = *reinterpret_cast<const float4*>(in + i);
        float4 b = *reinterpret_cast<const float4*>(in + i + 4);
        bf16x8 o;
        o[0] = (bf16_t)a.x; o[1] = (bf16_t)a.y;
        o[2] = (bf16_t)a.z; o[3] = (bf16_t)a.w;
        o[4] = (bf16_t)b.x; o[5] = (bf16_t)b.y;
        o[6] = (bf16_t)b.z; o[7] = (bf16_t)b.w;
        *reinterpret_cast<bf16x8*>(out + i) = o;
    }
}

// ---------------------------------------------------------------- GEMM 256x256 pipelined
__device__ __forceinline__ void gload16(const bf16_t* g, const char* l)
{
    __builtin_amdgcn_global_load_lds(
        (const __attribute__((address_space(1))) void*)g,
        (__attribute__((address_space(3))) void*)l, 16, 0, 0);
}

#define BAR() do { asm volatile("" ::: "memory"); \
                   __builtin_amdgcn_s_barrier(); \
                   asm volatile("" ::: "memory"); } while (0)

#define VMC(n) asm volatile("s_waitcnt vmcnt(" #n ")" ::: "memory")

#define LGKM0() do { asm volatile("s_waitcnt lgkmcnt(0)" ::: "memory"); \
                     __builtin_amdgcn_sched_barrier(0); } while (0)

// register fragment loads (ds_read_b128; compiler schedules lgkm waits)
#define RD_A0(bb) do { _Pragma("unroll") for (int m_ = 0; m_ < 4; ++m_) { \
    af0[m_][0] = *(const bf16x8*)(rdAk0 + (bb)*32768 + m_*2048); \
    af0[m_][1] = *(const bf16x8*)(rdAk1 + (bb)*32768 + m_*2048); } } while (0)

#define RD_AY(bb) do { _Pragma("unroll") for (int m_ = 0; m_ < 4; ++m_) { \
    afY[m_][0] = *(const bf16x8*)(rdAk0 + (bb)*32768 + 8192 + m_*2048); \
    afY[m_][1] = *(const bf16x8*)(rdAk1 + (bb)*32768 + 8192 + m_*2048); } } while (0)

#define RD_B01(bb) do { _Pragma("unroll") for (int n_ = 0; n_ < 2; ++n_) { \
    b01[n_][0] = *(const bf16x8*)(rdBk0 + (bb)*32768 + n_*2048); \
    b01[n_][1] = *(const bf16x8*)(rdBk1 + (bb)*32768 + n_*2048); } } while (0)

#define RD_B23(bb) do { _Pragma("unroll") for (int n_ = 0; n_ < 2; ++n_) { \
    b23[n_][0] = *(const bf16x8*)(rdBk0 + (bb)*32768 + 4096 + n_*2048); \
    b23[n_][1] = *(const bf16x8*)(rdBk1 + (bb)*32768 + 4096 + n_*2048); } } while (0)

// stage half-tile hf of K-tile u into buffer bb (predicated on u < nt)
#define ST_A(bb, hf, u) do { if ((u) < nt) { \
    const bf16_t* s_ = pA + (size_t)((hf)*128) * K + (size_t)(u)*64; \
    char* d_ = ldsAw + (bb)*32768 + (hf)*16384; \
    gload16(s_, d_); gload16(s_ + (size_t)8*K, d_ + 1024); } } while (0)

#define ST_B(bb, hf, u) do { if ((u) < nt) { \
    const bf16_t* s_ = pB + (size_t)((hf)*128) * K + (size_t)(u)*64; \
    char* d_ = ldsBw + (bb)*32768 + (hf)*16384; \
    gload16(s_, d_); gload16(s_ + (size_t)8*K, d_ + 1024); } } while (0)

// quadrant: 16 MFMA on (A_, B_) into acc[mo..mo+3][no..no+1]
#define MFQ(A_, B_, mo, no) do { __builtin_amdgcn_s_setprio(1); \
    _Pragma("unroll") for (int m_ = 0; m_ < 4; ++m_) \
    _Pragma("unroll") for (int n_ = 0; n_ < 2; ++n_) { \
        acc[(mo)+m_][(no)+n_] = __builtin_amdgcn_mfma_f32_16x16x32_bf16( \
            A_[m_][0], B_[n_][0], acc[(mo)+m_][(no)+n_], 0, 0, 0); \
        acc[(mo)+m_][(no)+n_] = __builtin_amdgcn_mfma_f32_16x16x32_bf16( \
            A_[m_][1], B_[n_][1], acc[(mo)+m_][(no)+n_], 0, 0, 0); } \
    __builtin_amdgcn_s_setprio(0); } while (0)

// C[M,N] = A[M,K] * Bt[N,K]^T ; 256x256 tile, BK=64, 8 waves (2Mx4N)
template <bool BF16_OUT, bool BIAS>
__global__ __launch_bounds__(512, 2) void gemm256(
    const bf16_t* __restrict__ A, const bf16_t* __restrict__ Bt,
    void* __restrict__ Cout, const float* __restrict__ bias,
    int M, int N, int K, int nx)
{
    __shared__ char smem[131072];   // A: [buf][half][128][64]bf16 @0, B same @65536

    const int tid  = threadIdx.x;
    const int lane = tid & 63;
    const int w    = tid >> 6;
    const int wr   = w >> 2;    // 0..1  -> rows wr*128
    const int wc   = w & 3;     // 0..3  -> cols wc*64

    // XCD-aware bijective swizzle (nwg % 8 == 0 for our launches)
    const int nwg = gridDim.x;
    int bid = blockIdx.x;
    if ((nwg & 7) == 0) bid = (bid & 7) * (nwg >> 3) + (bid >> 3);
    const int bx = bid % nx;
    const int by = bid / nx;
    const size_t bm = (size_t)by * 256;
    const size_t bn = (size_t)bx * 256;

    const int nt    = K >> 6;   // K/64 tiles
    const int niter = nt >> 1;  // 2 tiles per iteration (even nt)

    // ---- staging addresses (pre-swizzled global source, linear LDS dest)
    const int i3    = lane >> 3;                 // row within 8-row chunk
    const int colSw = ((lane & 7) ^ i3) * 8;     // inverse-swizzled source column
    const bf16_t* pA = A  + (bm + (size_t)(w * 16 + i3)) * K + colSw;
    const bf16_t* pB = Bt + (bn + (size_t)(w * 16 + i3)) * K + colSw;
    char* ldsAw = smem + w * 2048;
    char* ldsBw = smem + 65536 + w * 2048;

    // ---- read addresses (swizzle on read: byte ^= (row&7)<<4)
    const int lane_lo = lane & 15;
    const int sxr  = (lane & 7) << 4;
    const int cK0  = (((lane >> 4) * 16) ^ sxr);
    const int cK1  = cK0 ^ 64;
    const char* rdAk0 = smem + wr * 16384 + lane_lo * 128 + cK0;
    const char* rdAk1 = smem + wr * 16384 + lane_lo * 128 + cK1;
    const char* rdBk0 = smem + 65536 + (wc >> 1) * 16384 + ((wc & 1) * 64 + lane_lo) * 128 + cK0;
    const char* rdBk1 = smem + 65536 + (wc >> 1) * 16384 + ((wc & 1) * 64 + lane_lo) * 128 + cK1;

    f32x4  acc[8][4] = {};
    bf16x8 af0[4][2], afY[4][2], b01[2][2], b23[2][2];

    // ---- prologue: tile0 full; tile1 B-half0 + A-half0 stay in flight
    ST_B(0, 0, 0); ST_A(0, 0, 0); ST_A(0, 1, 0); ST_B(0, 1, 0);
    ST_B(1, 0, 1); ST_A(1, 0, 1);
    VMC(4);
    BAR();

    for (int it = 0; it < niter; ++it) {
        const int u = it * 2;
        const bool last = (it + 1 == niter);
        // ---- tile u (buf0): reads front-loaded, ph3/ph4 read-free
        RD_A0(0); RD_B01(0); RD_B23(0); ST_A(1, 1, u + 1); MFQ(af0, b01, 0, 0); BAR();
        RD_AY(0);                        ST_B(1, 1, u + 1); MFQ(af0, b23, 0, 2); BAR();
                                         ST_B(0, 0, u + 2); MFQ(afY, b01, 4, 0); BAR();
                                         ST_A(0, 0, u + 2); MFQ(afY, b23, 4, 2);
        if (last) { VMC(0); } else { VMC(4); }
        BAR();
        // ---- tile u+1 (buf1)
        RD_A0(1); RD_B01(1); RD_B23(1); ST_A(0, 1, u + 2); MFQ(af0, b01, 0, 0); BAR();
        RD_AY(1);                        ST_B(0, 1, u + 2); MFQ(af0, b23, 0, 2); BAR();
                                         ST_B(1, 0, u + 3); MFQ(afY, b01, 4, 0); BAR();
                                         ST_A(1, 0, u + 3); MFQ(afY, b23, 4, 2);
        if (last) { VMC(0); } else { VMC(4); }
        BAR();
    }

    // After the final VMC(0)+BAR: no ds_reads or global_load_lds pending
    // anywhere in the block -> smem is safe to reuse for the epilogue.
    const int crow = (lane >> 4) * 4;
    const int ccol = lane & 15;
    if constexpr (BF16_OUT) {
        // ---- epilogue via LDS: scalar ds_writes -> coalesced bf16x8 stores
        char* ep = smem + w * 16384;     // per-wave [128][64] bf16, row stride 128 B
        #pragma unroll
        for (int n = 0; n < 4; ++n) {
            const size_t col = bn + wc * 64 + n * 16 + ccol;
            float bv = 0.f;
            if constexpr (BIAS) bv = bias[col];
            #pragma unroll
            for (int m = 0; m < 8; ++m)
                #pragma unroll
                for (int r = 0; r < 4; ++r)
                    *(bf16_t*)(ep + (m * 16 + crow + r) * 128 + (n * 16 + ccol) * 2)
                        = (bf16_t)(acc[m][n][r] + bv);
        }
        LGKM0();   // wave-private region: own writes complete before own reads
        bf16_t* cb = (bf16_t*)Cout;
        #pragma unroll
        for (int pass = 0; pass < 16; ++pass) {
            const int rloc = pass * 8 + (lane >> 3);
            const int ch   = lane & 7;
            bf16x8 v = *(const bf16x8*)(ep + rloc * 128 + ch * 16);
            *(bf16x8*)((char*)(cb + (bm + wr * 128 + rloc) * (size_t)N + bn + wc * 64) + ch * 16) = v;
        }
    } else {
        // f32 path: 16 lanes x 4 B = contiguous 64-B segments already
        #pragma unroll
        for (int n = 0; n < 4; ++n) {
            const size_t col = bn + wc * 64 + n * 16 + ccol;
            float bv = 0.f;
            if constexpr (BIAS) bv = bias[col];
            #pragma unroll
            for (int m = 0; m < 8; ++m) {
                #pragma unroll
                for (int r = 0; r < 4; ++r) {
                    const size_t row = bm + wr * 128 + m * 16 + crow + r;
                    ((float*)Cout)[row * N + col] = acc[m][n][r] + bv;
                }
            }
        }
    }
}

// ---------------------------------------------------------------- attention
// One block per (b, h). 4 waves; wave owns 32 q-rows. T=128, D=64.
__global__ __launch_bounds__(256) void attn_kernel(
    const bf16_t* __restrict__ qkv, bf16_t* __restrict__ outp)
{
    __shared__ bf16_t Ks[128 * 64];    // [k_row][d], XOR-swizzled 16B slots
    __shared__ bf16_t Vt[64 * 128];    // [d][s], XOR-swizzled
    __shared__ bf16_t Ps[128 * 128];   // [m][s], XOR-swizzled; reused for output staging

    const int h    = blockIdx.x;
    const int b    = blockIdx.y;
    const int tid  = threadIdx.x;
    const int lane = tid & 63;
    const int wave = tid >> 6;

    const bf16_t* base = qkv + (size_t)b * T_SZ * NQKV + h * D_SZ;

    // ---- stage K [128][64] (swizzled) and V transposed -> Vt[64][128]
    #pragma unroll
    for (int p = 0; p < 4; ++p) {
        int e   = p * 256 + tid;       // 0..1023
        int row = e >> 3;              // 0..127 (s index)
        int col = (e & 7) * 8;         // 0..56  (d chunk)
        int4 kv = *reinterpret_cast<const int4*>(base + (size_t)row * NQKV + C_SZ + col);
        int kb = row * 128 + ((col * 2) ^ ((row & 7) << 4));
        *reinterpret_cast<int4*>((char*)Ks + kb) = kv;

        bf16x8 vv = *reinterpret_cast<const bf16x8*>(base + (size_t)row * NQKV + 2 * C_SZ + col);
        #pragma unroll
        for (int j = 0; j < 8; ++j) {
            int d  = col + j;
            int vb = d * 256 + ((row * 2) ^ ((d & 7) << 4));
            *reinterpret_cast<bf16_t*>((char*)Vt + vb) = vv[j];
        }
    }

    // ---- Q fragments for this wave's 32 rows (direct from global)
    bf16x8 qf[2][2];
    #pragma unroll
    for (int mi = 0; mi < 2; ++mi)
        #pragma unroll
        for (int ks = 0; ks < 2; ++ks) {
            int m = wave * 32 + mi * 16 + (lane & 15);
            int d = ks * 32 + (lane >> 4) * 8;
            qf[mi][ks] = *reinterpret_cast<const bf16x8*>(base + (size_t)m * NQKV + d);
        }

    __syncthreads();

    // ---- S = Q K^T  (per wave: [32,128] in acc)
    f32x4 s[2][8] = {};
    #pragma unroll
    for (int ks = 0; ks < 2; ++ks) {
        int koff = ks * 32 + (lane >> 4) * 8;   // d index
        #pragma unroll
        for (int nj = 0; nj < 8; ++nj) {
            int n  = nj * 16 + (lane & 15);
            int kb = n * 128 + ((koff * 2) ^ ((n & 7) << 4));
            bf16x8 kf = *reinterpret_cast<const bf16x8*>((char*)Ks + kb);
            #pragma unroll
            for (int mi = 0; mi < 2; ++mi)
                s[mi][nj] = __builtin_amdgcn_mfma_f32_16x16x32_bf16(
                    qf[mi][ks], kf, s[mi][nj], 0, 0, 0);
        }
    }

    // ---- causal mask + scale + softmax (row-wise), write P bf16 to LDS
    const float scale = 0.125f;   // 1/sqrt(64)
    #pragma unroll
    for (int mi = 0; mi < 2; ++mi) {
        #pragma unroll
        for (int r = 0; r < 4; ++r) {
            int m = wave * 32 + mi * 16 + ((lane >> 4) << 2) + r;
            float sv[8];
            float mx = -3.0e38f;
            #pragma unroll
            for (int nj = 0; nj < 8; ++nj) {
                int n   = nj * 16 + (lane & 15);
                float v = s[mi][nj][r] * scale;
                v = (n <= m) ? v : -3.0e38f;
                sv[nj] = v;
                mx = fmaxf(mx, v);
            }
            #pragma unroll
            for (int off = 1; off < 16; off <<= 1)
                mx = fmaxf(mx, __shfl_xor(mx, off));
            float sum = 0.f;
            #pragma unroll
            for (int nj = 0; nj < 8; ++nj) {
                float p = __expf(sv[nj] - mx);
                sv[nj] = p;
                sum += p;
            }
            #pragma unroll
            for (int off = 1; off < 16; off <<= 1)
                sum += __shfl_xor(sum, off);
            float inv = 1.0f / sum;
            #pragma unroll
            for (int nj = 0; nj < 8; ++nj) {
                int n  = nj * 16 + (lane & 15);
                int pb = m * 256 + ((n * 2) ^ ((m & 7) << 4));
                *reinterpret_cast<bf16_t*>((char*)Ps + pb) = (bf16_t)(sv[nj] * inv);
            }
        }
    }

    __syncthreads();

    // ---- O = P V   (per wave: [32,64])
    f32x4 o[2][4] = {};
    #pragma unroll
    for (int ks = 0; ks < 4; ++ks) {
        int soff = ks * 32 + (lane >> 4) * 8;   // s index
        bf16x8 pf[2];
        #pragma unroll
        for (int mi = 0; mi < 2; ++mi) {
            int m  = wave * 32 + mi * 16 + (lane & 15);
            int pb = m * 256 + ((soff * 2) ^ ((m & 7) << 4));
            pf[mi] = *reinterpret_cast<const bf16x8*>((char*)Ps + pb);
        }
        #pragma unroll
        for (int nj = 0; nj < 4; ++nj) {
            int d  = nj * 16 + (lane & 15);
            int vb = d * 256 + ((soff * 2) ^ ((d & 7) << 4));
            bf16x8 vf = *reinterpret_cast<const bf16x8*>((char*)Vt + vb);
            #pragma unroll
            for (int mi = 0; mi < 2; ++mi)
                o[mi][nj] = __builtin_amdgcn_mfma_f32_16x16x32_bf16(
                    pf[mi], vf, o[mi][nj], 0, 0, 0);
        }
    }

    __syncthreads();   // all Ps/Vt reads complete block-wide before reuse

    // ---- stage O into LDS (linear [128][64] bf16 in Ps region), then coalesced store
    char* on = (char*)Ps;
    #pragma unroll
    for (int mi = 0; mi < 2; ++mi)
        #pragma unroll
        for (int nj = 0; nj < 4; ++nj)
            #pragma unroll
            for (int r = 0; r < 4; ++r) {
                int m = wave * 32 + mi * 16 + ((lane >> 4) << 2) + r;
                int d = nj * 16 + (lane & 15);
                *(bf16_t*)(on + m * 128 + d * 2) = (bf16_t)o[mi][nj][r];
            }

    __syncthreads();

    // 128 rows x 128 B = 1024 x 16-B chunks; 4 passes x 256 threads x 16 B covers all
    bf16_t* op = outp + (size_t)b * T_SZ * C_SZ + h * D_SZ;
    #pragma unroll
    for (int pass = 0; pass < 4; ++pass) {
        int row = pass * 32 + (tid >> 3);    // 0..127
        int ch  = tid & 7;                   // 8 x 16 B = full 128-B row
        bf16x8 v = *(const bf16x8*)(on + row * 128 + ch * 16);
        *(bf16x8*)((char*)(op + (size_t)row * C_SZ) + ch * 16) = v;
    }
}

// ---------------------------------------------------------------- launch
extern "C" void kernel_launch(void* const* d_in, const int* in_sizes, int n_in,
                              void* d_out, int out_size, void* d_ws, size_t ws_size,
                              hipStream_t stream)
{
    const float* x      = (const float*)d_in[0];
    const float* w_qkv  = (const float*)d_in[1];
    const float* w_proj = (const float*)d_in[2];
    const float* b_proj = (const float*)d_in[3];

    const int n_x     = M_SZ * C_SZ;        // 50331648
    const int n_wqkv  = NQKV * C_SZ;        // 1769472
    const int n_wproj = C_SZ * C_SZ;        // 589824

    char* ws = (char*)d_ws;
    bf16_t* xb     = (bf16_t*)ws;                                   // 96 MB
    bf16_t* wqkvb  = (bf16_t*)(ws + (size_t)n_x * 2);
    bf16_t* wprojb = (bf16_t*)(ws + (size_t)n_x * 2 + (size_t)n_wqkv * 2);
    bf16_t* qkvb   = (bf16_t*)(ws + (size_t)n_x * 2 + (size_t)n_wqkv * 2 + (size_t)n_wproj * 2);
    bf16_t* attnb  = xb;   // xb is dead after GEMM1 — reuse region

    cvt_f32_bf16<<<4096, 256, 0, stream>>>(x, xb, n_x);
    cvt_f32_bf16<<<(n_wqkv / 8 + 255) / 256, 256, 0, stream>>>(w_qkv, wqkvb, n_wqkv);
    cvt_f32_bf16<<<(n_wproj / 8 + 255) / 256, 256, 0, stream>>>(w_proj, wprojb, n_wproj);

    gemm256<true, false><<<dim3((NQKV / 256) * (M_SZ / 256)), 512, 0, stream>>>(
        xb, wqkvb, qkvb, nullptr, M_SZ, NQKV, C_SZ, NQKV / 256);

    attn_kernel<<<dim3(H_SZ, B_SZ), 256, 0, stream>>>(qkvb, attnb);

    gemm256<false, true><<<dim3((C_SZ / 256) * (M_SZ / 256)), 512, 0, stream>>>(
        attnb, wprojb, d_out, b_proj, M_SZ, C_SZ, C_SZ, C_SZ / 256);
}

// Round 14
// 509.361 us; speedup vs baseline: 1.7470x; 1.0291x over previous
//
#include <hip/hip_runtime.h>
#include <hip/hip_bf16.h>

typedef __bf16 bf16_t;
typedef __attribute__((ext_vector_type(8))) __bf16 bf16x8;
typedef __attribute__((ext_vector_type(4))) float f32x4;

#define B_SZ 512
#define T_SZ 128
#define C_SZ 768
#define H_SZ 12
#define D_SZ 64
#define M_SZ (B_SZ * T_SZ)      // 65536
#define NQKV (3 * C_SZ)          // 2304

// ---------------------------------------------------------------- convert
__global__ __launch_bounds__(256) void cvt_f32_bf16(
    const float* __restrict__ in, bf16_t* __restrict__ out, int n)
{
    int i = (blockIdx.x * blockDim.x + threadIdx.x) * 8;
    int stride = gridDim.x * blockDim.x * 8;
    for (; i < n; i += stride) {
        float4 a = *reinterpret_cast<const float4*>(in + i);
        float4 b = *reinterpret_cast<const float4*>(in + i + 4);
        bf16x8 o;
        o[0] = (bf16_t)a.x; o[1] = (bf16_t)a.y;
        o[2] = (bf16_t)a.z; o[3] = (bf16_t)a.w;
        o[4] = (bf16_t)b.x; o[5] = (bf16_t)b.y;
        o[6] = (bf16_t)b.z; o[7] = (bf16_t)b.w;
        *reinterpret_cast<bf16x8*>(out + i) = o;
    }
}

// ---------------------------------------------------------------- GEMM 256x256 pipelined
__device__ __forceinline__ void gload16(const bf16_t* g, const char* l)
{
    __builtin_amdgcn_global_load_lds(
        (const __attribute__((address_space(1))) void*)g,
        (__attribute__((address_space(3))) void*)l, 16, 0, 0);
}

#define BAR() do { asm volatile("" ::: "memory"); \
                   __builtin_amdgcn_s_barrier(); \
                   asm volatile("" ::: "memory"); } while (0)

#define VMC(n) asm volatile("s_waitcnt vmcnt(" #n ")" ::: "memory")

#define LGKM0() do { asm volatile("s_waitcnt lgkmcnt(0)" ::: "memory"); \
                     __builtin_amdgcn_sched_barrier(0); } while (0)

// register fragment loads (ds_read_b128; compiler schedules lgkm waits)
#define RD_A0(bb) do { _Pragma("unroll") for (int m_ = 0; m_ < 4; ++m_) { \
    af0[m_][0] = *(const bf16x8*)(rdAk0 + (bb)*32768 + m_*2048); \
    af0[m_][1] = *(const bf16x8*)(rdAk1 + (bb)*32768 + m_*2048); } } while (0)

#define RD_AY(bb) do { _Pragma("unroll") for (int m_ = 0; m_ < 4; ++m_) { \
    afY[m_][0] = *(const bf16x8*)(rdAk0 + (bb)*32768 + 8192 + m_*2048); \
    afY[m_][1] = *(const bf16x8*)(rdAk1 + (bb)*32768 + 8192 + m_*2048); } } while (0)

#define RD_B01(bb) do { _Pragma("unroll") for (int n_ = 0; n_ < 2; ++n_) { \
    b01[n_][0] = *(const bf16x8*)(rdBk0 + (bb)*32768 + n_*2048); \
    b01[n_][1] = *(const bf16x8*)(rdBk1 + (bb)*32768 + n_*2048); } } while (0)

#define RD_B23(bb) do { _Pragma("unroll") for (int n_ = 0; n_ < 2; ++n_) { \
    b23[n_][0] = *(const bf16x8*)(rdBk0 + (bb)*32768 + 4096 + n_*2048); \
    b23[n_][1] = *(const bf16x8*)(rdBk1 + (bb)*32768 + 4096 + n_*2048); } } while (0)

// stage half-tile hf of K-tile u into buffer bb (predicated on u < nt)
#define ST_A(bb, hf, u) do { if ((u) < nt) { \
    const bf16_t* s_ = pA + (size_t)((hf)*128) * K + (size_t)(u)*64; \
    char* d_ = ldsAw + (bb)*32768 + (hf)*16384; \
    gload16(s_, d_); gload16(s_ + (size_t)8*K, d_ + 1024); } } while (0)

#define ST_B(bb, hf, u) do { if ((u) < nt) { \
    const bf16_t* s_ = pB + (size_t)((hf)*128) * K + (size_t)(u)*64; \
    char* d_ = ldsBw + (bb)*32768 + (hf)*16384; \
    gload16(s_, d_); gload16(s_ + (size_t)8*K, d_ + 1024); } } while (0)

// quadrant: 16 MFMA on (A_, B_) into acc[mo..mo+3][no..no+1]
// (no s_setprio: T5 is null-to-negative on lockstep barrier schedules, m190)
#define MFQ(A_, B_, mo, no) do { \
    _Pragma("unroll") for (int m_ = 0; m_ < 4; ++m_) \
    _Pragma("unroll") for (int n_ = 0; n_ < 2; ++n_) { \
        acc[(mo)+m_][(no)+n_] = __builtin_amdgcn_mfma_f32_16x16x32_bf16( \
            A_[m_][0], B_[n_][0], acc[(mo)+m_][(no)+n_], 0, 0, 0); \
        acc[(mo)+m_][(no)+n_] = __builtin_amdgcn_mfma_f32_16x16x32_bf16( \
            A_[m_][1], B_[n_][1], acc[(mo)+m_][(no)+n_], 0, 0, 0); } \
    } while (0)

// C[M,N] = A[M,K] * Bt[N,K]^T ; 256x256 tile, BK=64, 8 waves (2Mx4N)
template <bool BF16_OUT, bool BIAS>
__global__ __launch_bounds__(512, 2) void gemm256(
    const bf16_t* __restrict__ A, const bf16_t* __restrict__ Bt,
    void* __restrict__ Cout, const float* __restrict__ bias,
    int M, int N, int K, int nx)
{
    __shared__ char smem[131072];   // A: [buf][half][128][64]bf16 @0, B same @65536

    const int tid  = threadIdx.x;
    const int lane = tid & 63;
    const int w    = tid >> 6;
    const int wr   = w >> 2;    // 0..1  -> rows wr*128
    const int wc   = w & 3;     // 0..3  -> cols wc*64

    // XCD-aware bijective swizzle (nwg % 8 == 0 for our launches)
    const int nwg = gridDim.x;
    int bid = blockIdx.x;
    if ((nwg & 7) == 0) bid = (bid & 7) * (nwg >> 3) + (bid >> 3);
    const int bx = bid % nx;
    const int by = bid / nx;
    const size_t bm = (size_t)by * 256;
    const size_t bn = (size_t)bx * 256;

    const int nt    = K >> 6;   // K/64 tiles
    const int niter = nt >> 1;  // 2 tiles per iteration (even nt)

    // ---- staging addresses (pre-swizzled global source, linear LDS dest)
    const int i3    = lane >> 3;                 // row within 8-row chunk
    const int colSw = ((lane & 7) ^ i3) * 8;     // inverse-swizzled source column
    const bf16_t* pA = A  + (bm + (size_t)(w * 16 + i3)) * K + colSw;
    const bf16_t* pB = Bt + (bn + (size_t)(w * 16 + i3)) * K + colSw;
    char* ldsAw = smem + w * 2048;
    char* ldsBw = smem + 65536 + w * 2048;

    // ---- read addresses (swizzle on read: byte ^= (row&7)<<4)
    const int lane_lo = lane & 15;
    const int sxr  = (lane & 7) << 4;
    const int cK0  = (((lane >> 4) * 16) ^ sxr);
    const int cK1  = cK0 ^ 64;
    const char* rdAk0 = smem + wr * 16384 + lane_lo * 128 + cK0;
    const char* rdAk1 = smem + wr * 16384 + lane_lo * 128 + cK1;
    const char* rdBk0 = smem + 65536 + (wc >> 1) * 16384 + ((wc & 1) * 64 + lane_lo) * 128 + cK0;
    const char* rdBk1 = smem + 65536 + (wc >> 1) * 16384 + ((wc & 1) * 64 + lane_lo) * 128 + cK1;

    f32x4  acc[8][4] = {};
    bf16x8 af0[4][2], afY[4][2], b01[2][2], b23[2][2];

    // ---- prologue: tile0 full; tile1 B-half0 + A-half0 stay in flight
    ST_B(0, 0, 0); ST_A(0, 0, 0); ST_A(0, 1, 0); ST_B(0, 1, 0);
    ST_B(1, 0, 1); ST_A(1, 0, 1);
    VMC(4);
    BAR();

    for (int it = 0; it < niter; ++it) {
        const int u = it * 2;
        const bool last = (it + 1 == niter);
        // ---- tile u (buf0): reads front-loaded, ph3/ph4 read-free
        RD_A0(0); RD_B01(0); RD_B23(0); ST_A(1, 1, u + 1); MFQ(af0, b01, 0, 0); BAR();
        RD_AY(0);                        ST_B(1, 1, u + 1); MFQ(af0, b23, 0, 2); BAR();
                                         ST_B(0, 0, u + 2); MFQ(afY, b01, 4, 0); BAR();
                                         ST_A(0, 0, u + 2); MFQ(afY, b23, 4, 2);
        if (last) { VMC(0); } else { VMC(4); }
        BAR();
        // ---- tile u+1 (buf1)
        RD_A0(1); RD_B01(1); RD_B23(1); ST_A(0, 1, u + 2); MFQ(af0, b01, 0, 0); BAR();
        RD_AY(1);                        ST_B(0, 1, u + 2); MFQ(af0, b23, 0, 2); BAR();
                                         ST_B(1, 0, u + 3); MFQ(afY, b01, 4, 0); BAR();
                                         ST_A(1, 0, u + 3); MFQ(afY, b23, 4, 2);
        if (last) { VMC(0); } else { VMC(4); }
        BAR();
    }

    // After the final VMC(0)+BAR: no ds_reads or global_load_lds pending
    // anywhere in the block -> smem is safe to reuse for the epilogue.
    const int crow = (lane >> 4) * 4;
    const int ccol = lane & 15;
    if constexpr (BF16_OUT) {
        // ---- epilogue via LDS: scalar ds_writes -> coalesced bf16x8 stores.
        // Bank swizzle: sw = ((row&7)<<4) ^ (((row>>3)&1)<<5) spreads the 4
        // row-groups of each store instruction across all 32 banks (was 8-way).
        char* ep = smem + w * 16384;     // per-wave [128][64] bf16, row stride 128 B
        #pragma unroll
        for (int n = 0; n < 4; ++n) {
            const size_t col = bn + wc * 64 + n * 16 + ccol;
            float bv = 0.f;
            if constexpr (BIAS) bv = bias[col];
            #pragma unroll
            for (int m = 0; m < 8; ++m)
                #pragma unroll
                for (int r = 0; r < 4; ++r) {
                    const int rowloc = m * 16 + crow + r;
                    const int sw = ((rowloc & 7) << 4) ^ (((rowloc >> 3) & 1) << 5);
                    *(bf16_t*)(ep + rowloc * 128 + (((n * 16 + ccol) * 2) ^ sw))
                        = (bf16_t)(acc[m][n][r] + bv);
                }
        }
        LGKM0();   // wave-private region: own writes complete before own reads
        bf16_t* cb = (bf16_t*)Cout;
        #pragma unroll
        for (int pass = 0; pass < 16; ++pass) {
            const int rloc = pass * 8 + (lane >> 3);
            const int ch   = lane & 7;
            const int sw   = ((rloc & 7) << 4) ^ (((rloc >> 3) & 1) << 5);
            bf16x8 v = *(const bf16x8*)(ep + rloc * 128 + ((ch * 16) ^ sw));
            *(bf16x8*)((char*)(cb + (bm + wr * 128 + rloc) * (size_t)N + bn + wc * 64) + ch * 16) = v;
        }
    } else {
        // f32 path: 16 lanes x 4 B = contiguous 64-B segments already
        #pragma unroll
        for (int n = 0; n < 4; ++n) {
            const size_t col = bn + wc * 64 + n * 16 + ccol;
            float bv = 0.f;
            if constexpr (BIAS) bv = bias[col];
            #pragma unroll
            for (int m = 0; m < 8; ++m) {
                #pragma unroll
                for (int r = 0; r < 4; ++r) {
                    const size_t row = bm + wr * 128 + m * 16 + crow + r;
                    ((float*)Cout)[row * N + col] = acc[m][n][r] + bv;
                }
            }
        }
    }
}

// ---------------------------------------------------------------- attention
// One block per (b, h). 4 waves; wave owns 32 q-rows. T=128, D=64.
__global__ __launch_bounds__(256) void attn_kernel(
    const bf16_t* __restrict__ qkv, bf16_t* __restrict__ outp)
{
    __shared__ bf16_t Ks[128 * 64];    // [k_row][d], XOR-swizzled 16B slots
    __shared__ bf16_t Vt[64 * 128];    // [d][s], XOR-swizzled
    __shared__ bf16_t Ps[128 * 128];   // [m][s], XOR-swizzled; reused for output staging

    const int h    = blockIdx.x;
    const int b    = blockIdx.y;
    const int tid  = threadIdx.x;
    const int lane = tid & 63;
    const int wave = tid >> 6;

    const bf16_t* base = qkv + (size_t)b * T_SZ * NQKV + h * D_SZ;

    // ---- stage K [128][64] (swizzled) and V transposed -> Vt[64][128]
    #pragma unroll
    for (int p = 0; p < 4; ++p) {
        int e   = p * 256 + tid;       // 0..1023
        int row = e >> 3;              // 0..127 (s index)
        int col = (e & 7) * 8;         // 0..56  (d chunk)
        int4 kv = *reinterpret_cast<const int4*>(base + (size_t)row * NQKV + C_SZ + col);
        int kb = row * 128 + ((col * 2) ^ ((row & 7) << 4));
        *reinterpret_cast<int4*>((char*)Ks + kb) = kv;

        bf16x8 vv = *reinterpret_cast<const bf16x8*>(base + (size_t)row * NQKV + 2 * C_SZ + col);
        #pragma unroll
        for (int j = 0; j < 8; ++j) {
            int d  = col + j;
            int vb = d * 256 + ((row * 2) ^ ((d & 7) << 4));
            *reinterpret_cast<bf16_t*>((char*)Vt + vb) = vv[j];
        }
    }

    // ---- Q fragments for this wave's 32 rows (direct from global)
    bf16x8 qf[2][2];
    #pragma unroll
    for (int mi = 0; mi < 2; ++mi)
        #pragma unroll
        for (int ks = 0; ks < 2; ++ks) {
            int m = wave * 32 + mi * 16 + (lane & 15);
            int d = ks * 32 + (lane >> 4) * 8;
            qf[mi][ks] = *reinterpret_cast<const bf16x8*>(base + (size_t)m * NQKV + d);
        }

    __syncthreads();

    // ---- S = Q K^T  (per wave: [32,128] in acc)
    f32x4 s[2][8] = {};
    #pragma unroll
    for (int ks = 0; ks < 2; ++ks) {
        int koff = ks * 32 + (lane >> 4) * 8;   // d index
        #pragma unroll
        for (int nj = 0; nj < 8; ++nj) {
            int n  = nj * 16 + (lane & 15);
            int kb = n * 128 + ((koff * 2) ^ ((n & 7) << 4));
            bf16x8 kf = *reinterpret_cast<const bf16x8*>((char*)Ks + kb);
            #pragma unroll
            for (int mi = 0; mi < 2; ++mi)
                s[mi][nj] = __builtin_amdgcn_mfma_f32_16x16x32_bf16(
                    qf[mi][ks], kf, s[mi][nj], 0, 0, 0);
        }
    }

    // ---- causal mask + scale + softmax (row-wise), write P bf16 to LDS
    const float scale = 0.125f;   // 1/sqrt(64)
    #pragma unroll
    for (int mi = 0; mi < 2; ++mi) {
        #pragma unroll
        for (int r = 0; r < 4; ++r) {
            int m = wave * 32 + mi * 16 + ((lane >> 4) << 2) + r;
            float sv[8];
            float mx = -3.0e38f;
            #pragma unroll
            for (int nj = 0; nj < 8; ++nj) {
                int n   = nj * 16 + (lane & 15);
                float v = s[mi][nj][r] * scale;
                v = (n <= m) ? v : -3.0e38f;
                sv[nj] = v;
                mx = fmaxf(mx, v);
            }
            #pragma unroll
            for (int off = 1; off < 16; off <<= 1)
                mx = fmaxf(mx, __shfl_xor(mx, off));
            float sum = 0.f;
            #pragma unroll
            for (int nj = 0; nj < 8; ++nj) {
                float p = __expf(sv[nj] - mx);
                sv[nj] = p;
                sum += p;
            }
            #pragma unroll
            for (int off = 1; off < 16; off <<= 1)
                sum += __shfl_xor(sum, off);
            float inv = 1.0f / sum;
            #pragma unroll
            for (int nj = 0; nj < 8; ++nj) {
                int n  = nj * 16 + (lane & 15);
                int pb = m * 256 + ((n * 2) ^ ((m & 7) << 4));
                *reinterpret_cast<bf16_t*>((char*)Ps + pb) = (bf16_t)(sv[nj] * inv);
            }
        }
    }

    __syncthreads();

    // ---- O = P V   (per wave: [32,64])
    f32x4 o[2][4] = {};
    #pragma unroll
    for (int ks = 0; ks < 4; ++ks) {
        int soff = ks * 32 + (lane >> 4) * 8;   // s index
        bf16x8 pf[2];
        #pragma unroll
        for (int mi = 0; mi < 2; ++mi) {
            int m  = wave * 32 + mi * 16 + (lane & 15);
            int pb = m * 256 + ((soff * 2) ^ ((m & 7) << 4));
            pf[mi] = *reinterpret_cast<const bf16x8*>((char*)Ps + pb);
        }
        #pragma unroll
        for (int nj = 0; nj < 4; ++nj) {
            int d  = nj * 16 + (lane & 15);
            int vb = d * 256 + ((soff * 2) ^ ((d & 7) << 4));
            bf16x8 vf = *reinterpret_cast<const bf16x8*>((char*)Vt + vb);
            #pragma unroll
            for (int mi = 0; mi < 2; ++mi)
                o[mi][nj] = __builtin_amdgcn_mfma_f32_16x16x32_bf16(
                    pf[mi], vf, o[mi][nj], 0, 0, 0);
        }
    }

    __syncthreads();   // all Ps/Vt reads complete block-wide before reuse

    // ---- stage O into LDS (linear [128][64] bf16 in Ps region), then coalesced store
    char* on = (char*)Ps;
    #pragma unroll
    for (int mi = 0; mi < 2; ++mi)
        #pragma unroll
        for (int nj = 0; nj < 4; ++nj)
            #pragma unroll
            for (int r = 0; r < 4; ++r) {
                int m = wave * 32 + mi * 16 + ((lane >> 4) << 2) + r;
                int d = nj * 16 + (lane & 15);
                *(bf16_t*)(on + m * 128 + d * 2) = (bf16_t)o[mi][nj][r];
            }

    __syncthreads();

    // 128 rows x 128 B = 1024 x 16-B chunks; 4 passes x 256 threads x 16 B covers all
    bf16_t* op = outp + (size_t)b * T_SZ * C_SZ + h * D_SZ;
    #pragma unroll
    for (int pass = 0; pass < 4; ++pass) {
        int row = pass * 32 + (tid >> 3);    // 0..127
        int ch  = tid & 7;                   // 8 x 16 B = full 128-B row
        bf16x8 v = *(const bf16x8*)(on + row * 128 + ch * 16);
        *(bf16x8*)((char*)(op + (size_t)row * C_SZ) + ch * 16) = v;
    }
}

// ---------------------------------------------------------------- launch
extern "C" void kernel_launch(void* const* d_in, const int* in_sizes, int n_in,
                              void* d_out, int out_size, void* d_ws, size_t ws_size,
                              hipStream_t stream)
{
    const float* x      = (const float*)d_in[0];
    const float* w_qkv  = (const float*)d_in[1];
    const float* w_proj = (const float*)d_in[2];
    const float* b_proj = (const float*)d_in[3];

    const int n_x     = M_SZ * C_SZ;        // 50331648
    const int n_wqkv  = NQKV * C_SZ;        // 1769472
    const int n_wproj = C_SZ * C_SZ;        // 589824

    char* ws = (char*)d_ws;
    bf16_t* xb     = (bf16_t*)ws;                                   // 96 MB
    bf16_t* wqkvb  = (bf16_t*)(ws + (size_t)n_x * 2);
    bf16_t* wprojb = (bf16_t*)(ws + (size_t)n_x * 2 + (size_t)n_wqkv * 2);
    bf16_t* qkvb   = (bf16_t*)(ws + (size_t)n_x * 2 + (size_t)n_wqkv * 2 + (size_t)n_wproj * 2);
    bf16_t* attnb  = xb;   // xb is dead after GEMM1 — reuse region

    cvt_f32_bf16<<<4096, 256, 0, stream>>>(x, xb, n_x);
    cvt_f32_bf16<<<(n_wqkv / 8 + 255) / 256, 256, 0, stream>>>(w_qkv, wqkvb, n_wqkv);
    cvt_f32_bf16<<<(n_wproj / 8 + 255) / 256, 256, 0, stream>>>(w_proj, wprojb, n_wproj);

    gemm256<true, false><<<dim3((NQKV / 256) * (M_SZ / 256)), 512, 0, stream>>>(
        xb, wqkvb, qkvb, nullptr, M_SZ, NQKV, C_SZ, NQKV / 256);

    attn_kernel<<<dim3(H_SZ, B_SZ), 256, 0, stream>>>(qkvb, attnb);

    gemm256<false, true><<<dim3((C_SZ / 256) * (M_SZ / 256)), 512, 0, stream>>>(
        attnb, wprojb, d_out, b_proj, M_SZ, C_SZ, C_SZ, C_SZ / 256);
}